// Round 2
// baseline (1274.782 us; speedup 1.0000x reference)
//
#include <hip/hip_runtime.h>
#include <math.h>

#define LVL 24
#define TMASK ((1u << 19) - 1u)

typedef short short8 __attribute__((ext_vector_type(8)));
typedef float floatx4 __attribute__((ext_vector_type(4)));

struct ResParams { float r[LVL]; };

__device__ __forceinline__ float bf2f(unsigned short b) {
  union { unsigned u; float f; } t; t.u = ((unsigned)b) << 16; return t.f;
}
__device__ __forceinline__ unsigned short f2bf(float f) {
  union { float f; unsigned u; } t; t.f = f;
  unsigned u = t.u;
  u += 0x7FFFu + ((u >> 16) & 1u);   // RNE
  return (unsigned short)(u >> 16);
}
__device__ __forceinline__ float geluf(float x) {
  return 0.5f * x * (1.0f + erff(x * 0.7071067811865476f));
}
__device__ __forceinline__ floatx4 mfma16(short8 a, short8 b, floatx4 c) {
  return __builtin_amdgcn_mfma_f32_16x16x32_bf16(a, b, c, 0, 0, 0);
}

template<bool F32>
__device__ __forceinline__ float ldf(const void* p, int i) {
  if constexpr (F32) return ((const float*)p)[i];
  else return bf2f(((const unsigned short*)p)[i]);
}
template<bool F32>
__device__ __forceinline__ void stf(void* o, int i, float v) {
  if constexpr (F32) ((float*)o)[i] = v;
  else ((unsigned short*)o)[i] = f2bf(v);
}

// LDS weight offsets (shorts). Stage1: fw0..fw3. Stage2 (reuse): rw0..rw2.
#define W0_OFF 0
#define W1_OFF 4608
#define W2_OFF 9216
#define W3_OFF 13824   // 80 rows x 72
#define R0_OFF 0       // 64 rows x 104
#define R1_OFF 6656
#define R2_OFF 11264   // 16 rows x 72

template<bool F32, int K, int NOUT, int NROWS, int STRIDE>
__device__ void stageW(const void* w, short* dst, int tid) {
  for (int i = tid; i < NROWS * STRIDE; i += 256) {
    int n = i / STRIDE;
    int k = i - n * STRIDE;
    short v = 0;
    if (n < NOUT && k < K) v = (short)f2bf(ldf<F32>(w, k * NOUT + n));
    dst[i] = v;
  }
}
template<bool F32, int NOUT, int NPAD>
__device__ void stageB(const void* b, float* dst, int tid) {
  for (int i = tid; i < NPAD; i += 256) dst[i] = (i < NOUT) ? ldf<F32>(b, i) : 0.0f;
}

template<int KCH, int CBS, int WSTRIDE>
__device__ __forceinline__ void run_layer(const short* At, const short* Wb,
                                          int m, int quad, floatx4* acc) {
  #pragma unroll
  for (int cb = 0; cb < CBS; ++cb) acc[cb] = (floatx4){0.f, 0.f, 0.f, 0.f};
  #pragma unroll
  for (int c = 0; c < KCH; ++c) {
    short8 a = *(const short8*)(At + m * 104 + c * 32 + quad * 8);
    #pragma unroll
    for (int cb = 0; cb < CBS; ++cb) {
      short8 b = *(const short8*)(Wb + (cb * 16 + m) * WSTRIDE + c * 32 + quad * 8);
      acc[cb] = mfma16(a, b, acc[cb]);
    }
  }
}

// Probe: decide whether tensors are f32 (flag=1) or bf16 (flag=0) by sanity
// of fw0 interpreted as f32 (uniform(-0.144,0.144) => all |v| < 1; bf16 pairs
// misread as f32 => magnitudes ~2^100).
__global__ void dtype_probe(const float* fw0, int* flag) {
  if (threadIdx.x == 0 && blockIdx.x == 0) {
    int ok = 1;
    for (int i = 0; i < 256; ++i) {
      float v = fw0[i];
      if (!(fabsf(v) < 1.0f)) { ok = 0; break; }
    }
    *flag = ok;
  }
}

template<bool F32>
__global__ __launch_bounds__(256, 2) void nerf_fused(
    const void* __restrict__ pts,
    const void* __restrict__ dirs,
    const void* __restrict__ tbl,
    const void* __restrict__ fw0, const void* __restrict__ fb0,
    const void* __restrict__ fw1, const void* __restrict__ fb1,
    const void* __restrict__ fw2, const void* __restrict__ fb2,
    const void* __restrict__ fw3, const void* __restrict__ fb3,
    const void* __restrict__ rw0, const void* __restrict__ rb0,
    const void* __restrict__ rw1, const void* __restrict__ rb1,
    const void* __restrict__ rw2, const void* __restrict__ rb2,
    void* __restrict__ outp, int Nrows, ResParams rp, const int* __restrict__ flag)
{
  if (*(const volatile int*)flag != (F32 ? 1 : 0)) return;

  __shared__ __align__(16) short Wlds[19584];
  __shared__ float Blds[272];
  __shared__ __align__(16) short Atile[4 * 16 * 104];

  const int tid  = threadIdx.x;
  const int wave = tid >> 6;
  const int lane = tid & 63;
  const int m    = lane & 15;
  const int quad = lane >> 4;
  const int row0 = blockIdx.x * 64 + wave * 16;
  short* At = Atile + wave * (16 * 104);

  // ---- stage 1 weights + biases (whole block) ----
  stageW<F32, 48, 64, 64, 72>(fw0, Wlds + W0_OFF, tid);
  stageW<F32, 64, 64, 64, 72>(fw1, Wlds + W1_OFF, tid);
  stageW<F32, 64, 64, 64, 72>(fw2, Wlds + W2_OFF, tid);
  stageW<F32, 64, 65, 80, 72>(fw3, Wlds + W3_OFF, tid);
  stageB<F32, 64, 64>(fb0, Blds + 0,   tid);
  stageB<F32, 64, 64>(fb1, Blds + 64,  tid);
  stageB<F32, 64, 64>(fb2, Blds + 128, tid);
  stageB<F32, 65, 80>(fb3, Blds + 192, tid);

  // ---- per-wave A-tile init: SH3 dirs at k=64..72, zeros k=48..63 / 73..103 ----
  if (lane < 16) {
    int row = row0 + lane;
    float dx = ldf<F32>(dirs, row * 3 + 0);
    float dy = ldf<F32>(dirs, row * 3 + 1);
    float dz = ldf<F32>(dirs, row * 3 + 2);
    short8 z8 = {0, 0, 0, 0, 0, 0, 0, 0};
    short8 s07;
    s07[0] = (short)f2bf(0.28209479177387814f);
    s07[1] = (short)f2bf(-0.48860251190291987f * dy);
    s07[2] = (short)f2bf(0.48860251190291987f * dz);
    s07[3] = (short)f2bf(-0.48860251190291987f * dx);
    s07[4] = (short)f2bf(1.0925484305920792f * dx * dy);
    s07[5] = (short)f2bf(-1.0925484305920792f * dy * dz);
    s07[6] = (short)f2bf(0.31539156525252005f * (3.0f * dz * dz - 1.0f));
    s07[7] = (short)f2bf(-1.0925484305920792f * dx * dz);
    short8 s8v = {0, 0, 0, 0, 0, 0, 0, 0};
    s8v[0] = (short)f2bf(0.5462742152960396f * (dx * dx - dy * dy));
    short* rb = At + lane * 104;
    *(short8*)(rb + 48) = z8;
    *(short8*)(rb + 56) = z8;
    *(short8*)(rb + 64) = s07;
    *(short8*)(rb + 72) = s8v;
    *(short8*)(rb + 80) = z8;
    *(short8*)(rb + 88) = z8;
    *(short8*)(rb + 96) = z8;
  }

  // ---- hash-grid encode: 16 rows x 24 levels per wave, A-tile k=0..47 ----
  for (int t = lane; t < 16 * LVL; t += 64) {
    int r = t / LVL;
    int l = t - r * LVL;
    int row = row0 + r;
    float res = rp.r[l];
    float w0, w1, w2;
    unsigned ha0, hb0, ha1, hb1, ha2, hb2;
    {
      float x  = (ldf<F32>(pts, row * 3 + 0) + 1.0f) * 0.5f;
      float p  = x * res;
      float fl = floorf(p);
      w0 = p - fl;
      unsigned c = (unsigned)fl;
      ha0 = c; hb0 = c + 1u;
    }
    {
      float x  = (ldf<F32>(pts, row * 3 + 1) + 1.0f) * 0.5f;
      float p  = x * res;
      float fl = floorf(p);
      w1 = p - fl;
      unsigned c = (unsigned)fl;
      ha1 = c * 2654435761u; hb1 = (c + 1u) * 2654435761u;
    }
    {
      float x  = (ldf<F32>(pts, row * 3 + 2) + 1.0f) * 0.5f;
      float p  = x * res;
      float fl = floorf(p);
      w2 = p - fl;
      unsigned c = (unsigned)fl;
      ha2 = c * 805459861u; hb2 = (c + 1u) * 805459861u;
    }
    float f0 = 0.f, f1 = 0.f;
    #pragma unroll
    for (int i = 0; i < 8; ++i) {
      unsigned h  = ((i & 4) ? hb0 : ha0) ^ ((i & 2) ? hb1 : ha1) ^ ((i & 1) ? hb2 : ha2);
      float wt = ((i & 4) ? w0 : 1.f - w0) * ((i & 2) ? w1 : 1.f - w1) * ((i & 1) ? w2 : 1.f - w2);
      if constexpr (F32) {
        const float* tb = (const float*)tbl + ((size_t)l << 20);
        float2 fv = *(const float2*)(tb + 2u * (h & TMASK));
        f0 += wt * fv.x;
        f1 += wt * fv.y;
      } else {
        const unsigned* tb = (const unsigned*)tbl + ((unsigned)l << 19);
        unsigned fv = tb[h & TMASK];
        f0 += wt * bf2f((unsigned short)(fv & 0xffffu));
        f1 += wt * bf2f((unsigned short)(fv >> 16));
      }
    }
    unsigned pk = (unsigned)f2bf(f0) | ((unsigned)f2bf(f1) << 16);
    *(unsigned*)(At + r * 104 + 2 * l) = pk;
  }

  __syncthreads();

  floatx4 acc[5];

  // L0
  run_layer<2, 4, 72>(At, Wlds + W0_OFF, m, quad, acc);
  #pragma unroll
  for (int cb = 0; cb < 4; ++cb) {
    float bc = Blds[0 + cb * 16 + m];
    #pragma unroll
    for (int r = 0; r < 4; ++r) {
      float v = geluf(acc[cb][r] + bc);
      At[(quad * 4 + r) * 104 + cb * 16 + m] = (short)f2bf(v);
    }
  }
  // L1
  run_layer<2, 4, 72>(At, Wlds + W1_OFF, m, quad, acc);
  #pragma unroll
  for (int cb = 0; cb < 4; ++cb) {
    float bc = Blds[64 + cb * 16 + m];
    #pragma unroll
    for (int r = 0; r < 4; ++r) {
      float v = geluf(acc[cb][r] + bc);
      At[(quad * 4 + r) * 104 + cb * 16 + m] = (short)f2bf(v);
    }
  }
  // L2
  run_layer<2, 4, 72>(At, Wlds + W2_OFF, m, quad, acc);
  #pragma unroll
  for (int cb = 0; cb < 4; ++cb) {
    float bc = Blds[128 + cb * 16 + m];
    #pragma unroll
    for (int r = 0; r < 4; ++r) {
      float v = geluf(acc[cb][r] + bc);
      At[(quad * 4 + r) * 104 + cb * 16 + m] = (short)f2bf(v);
    }
  }
  // L3: 64 -> 65 ; col0 -> softplus -> density ; cols 1..64 -> gelu -> k=0..63
  run_layer<2, 5, 72>(At, Wlds + W3_OFF, m, quad, acc);
  #pragma unroll
  for (int cb = 0; cb < 5; ++cb) {
    int col = cb * 16 + m;
    float bc = Blds[192 + col];
    #pragma unroll
    for (int r = 0; r < 4; ++r) {
      float v = acc[cb][r] + bc;
      int row = quad * 4 + r;
      if (col == 0) {
        float d = (v > 15.f) ? v : log1pf(expf(v));
        stf<F32>(outp, 3 * Nrows + row0 + row, d);
      } else if (col <= 64) {
        At[row * 104 + (col - 1)] = (short)f2bf(geluf(v));
      }
    }
  }

  __syncthreads();

  // ---- stage 2 weights + biases (overwrite union) ----
  stageW<F32, 73, 64, 64, 104>(rw0, Wlds + R0_OFF, tid);
  stageW<F32, 64, 64, 64,  72>(rw1, Wlds + R1_OFF, tid);
  stageW<F32, 64,  3, 16,  72>(rw2, Wlds + R2_OFF, tid);
  stageB<F32, 64, 64>(rb0, Blds + 0,   tid);
  stageB<F32, 64, 64>(rb1, Blds + 64,  tid);
  stageB<F32,  3, 16>(rb2, Blds + 128, tid);

  __syncthreads();

  // L4: [feat64 | sh9 | 0pad] (K=96) -> 64, gelu
  run_layer<3, 4, 104>(At, Wlds + R0_OFF, m, quad, acc);
  #pragma unroll
  for (int cb = 0; cb < 4; ++cb) {
    float bc = Blds[0 + cb * 16 + m];
    #pragma unroll
    for (int r = 0; r < 4; ++r) {
      float v = geluf(acc[cb][r] + bc);
      At[(quad * 4 + r) * 104 + cb * 16 + m] = (short)f2bf(v);
    }
  }
  // L5
  run_layer<2, 4, 72>(At, Wlds + R1_OFF, m, quad, acc);
  #pragma unroll
  for (int cb = 0; cb < 4; ++cb) {
    float bc = Blds[64 + cb * 16 + m];
    #pragma unroll
    for (int r = 0; r < 4; ++r) {
      float v = geluf(acc[cb][r] + bc);
      At[(quad * 4 + r) * 104 + cb * 16 + m] = (short)f2bf(v);
    }
  }
  // L6: 64 -> 3, sigmoid -> rgb
  run_layer<2, 1, 72>(At, Wlds + R2_OFF, m, quad, acc);
  {
    float bc = Blds[128 + m];
    #pragma unroll
    for (int r = 0; r < 4; ++r) {
      float v = acc[0][r] + bc;
      float s = 1.0f / (1.0f + expf(-v));
      if (m < 3) stf<F32>(outp, (row0 + quad * 4 + r) * 3 + m, s);
    }
  }
}

extern "C" void kernel_launch(void* const* d_in, const int* in_sizes, int n_in,
                              void* d_out, int out_size, void* d_ws, size_t ws_size,
                              hipStream_t stream) {
  ResParams rp;
  double b = exp((log(2048.0) - log(16.0)) / 23.0);
  for (int l = 0; l < LVL; ++l) rp.r[l] = (float)floor(16.0 * pow(b, (double)l));

  int n = in_sizes[0] / 3;       // 524288
  int blocks = n / 64;           // 8192
  int* flag = (int*)d_ws;

  dtype_probe<<<1, 64, 0, stream>>>((const float*)d_in[3], flag);

  nerf_fused<true><<<blocks, 256, 0, stream>>>(
      d_in[0], d_in[1], d_in[2],
      d_in[3], d_in[4], d_in[5], d_in[6], d_in[7], d_in[8], d_in[9], d_in[10],
      d_in[11], d_in[12], d_in[13], d_in[14], d_in[15], d_in[16],
      d_out, n, rp, flag);

  nerf_fused<false><<<blocks, 256, 0, stream>>>(
      d_in[0], d_in[1], d_in[2],
      d_in[3], d_in[4], d_in[5], d_in[6], d_in[7], d_in[8], d_in[9], d_in[10],
      d_in[11], d_in[12], d_in[13], d_in[14], d_in[15], d_in[16],
      d_out, n, rp, flag);
}

// Round 3
// 966.396 us; speedup vs baseline: 1.3191x; 1.3191x over previous
//
#include <hip/hip_runtime.h>
#include <math.h>

#define LVL 24
#define TMASK ((1u << 19) - 1u)

typedef short short8 __attribute__((ext_vector_type(8)));
typedef float floatx4 __attribute__((ext_vector_type(4)));

struct ResParams { float r[LVL]; };

__device__ __forceinline__ unsigned short f2bf(float f) {
  union { float f; unsigned u; } t; t.f = f;
  unsigned u = t.u;
  u += 0x7FFFu + ((u >> 16) & 1u);   // RNE
  return (unsigned short)(u >> 16);
}
__device__ __forceinline__ float geluf(float x) {
  return 0.5f * x * (1.0f + erff(x * 0.7071067811865476f));
}
__device__ __forceinline__ floatx4 mfma16(short8 a, short8 b, floatx4 c) {
  return __builtin_amdgcn_mfma_f32_16x16x32_bf16(a, b, c, 0, 0, 0);
}

// LDS weight offsets (shorts). Stage1: fw0..fw3. Stage2 (reuse): rw0..rw2.
#define W0_OFF 0
#define W1_OFF 4608
#define W2_OFF 9216
#define W3_OFF 13824   // 80 rows x 72
#define R0_OFF 0       // 64 rows x 104
#define R1_OFF 6656
#define R2_OFF 11264   // 16 rows x 72

template<int K, int NOUT, int NROWS, int STRIDE>
__device__ void stageW(const float* w, short* dst, int tid) {
  for (int i = tid; i < NROWS * STRIDE; i += 256) {
    int n = i / STRIDE;
    int k = i - n * STRIDE;
    short v = 0;
    if (n < NOUT && k < K) v = (short)f2bf(w[k * NOUT + n]);
    dst[i] = v;
  }
}
template<int NOUT, int NPAD>
__device__ void stageB(const float* b, float* dst, int tid) {
  for (int i = tid; i < NPAD; i += 256) dst[i] = (i < NOUT) ? b[i] : 0.0f;
}

template<int KCH, int CBS, int WSTRIDE>
__device__ __forceinline__ void run_layer(const short* At, const short* Wb,
                                          int m, int quad, floatx4* acc) {
  #pragma unroll
  for (int cb = 0; cb < CBS; ++cb) acc[cb] = (floatx4){0.f, 0.f, 0.f, 0.f};
  #pragma unroll
  for (int c = 0; c < KCH; ++c) {
    short8 a = *(const short8*)(At + m * 104 + c * 32 + quad * 8);
    #pragma unroll
    for (int cb = 0; cb < CBS; ++cb) {
      short8 b = *(const short8*)(Wb + (cb * 16 + m) * WSTRIDE + c * 32 + quad * 8);
      acc[cb] = mfma16(a, b, acc[cb]);
    }
  }
}

// ---------------------------------------------------------------------------
// Kernel A: hash-grid encode. One thread per (level, point). Level-major grid
// ordering so each XCD's L2 holds ~one 4MB table slice at a time.
// Output enc2[l*N + p] = packed bf16 (f0, f1), fully coalesced stores.
// ---------------------------------------------------------------------------
__global__ __launch_bounds__(256) void hash_encode_k(
    const float* __restrict__ pts, const float* __restrict__ tbl,
    unsigned* __restrict__ enc2, int N, ResParams rp)
{
  int bid = blockIdx.x;
  int l   = bid >> 11;                       // 2048 blocks per level
  int p   = ((bid & 2047) << 8) + threadIdx.x;
  float res = rp.r[l];

  float w0, w1, w2;
  unsigned ha0, hb0, ha1, hb1, ha2, hb2;
  {
    float x  = (pts[p * 3 + 0] + 1.0f) * 0.5f;
    float po = x * res;
    float fl = floorf(po);
    w0 = po - fl;
    unsigned c = (unsigned)fl;
    ha0 = c; hb0 = c + 1u;
  }
  {
    float x  = (pts[p * 3 + 1] + 1.0f) * 0.5f;
    float po = x * res;
    float fl = floorf(po);
    w1 = po - fl;
    unsigned c = (unsigned)fl;
    ha1 = c * 2654435761u; hb1 = (c + 1u) * 2654435761u;
  }
  {
    float x  = (pts[p * 3 + 2] + 1.0f) * 0.5f;
    float po = x * res;
    float fl = floorf(po);
    w2 = po - fl;
    unsigned c = (unsigned)fl;
    ha2 = c * 805459861u; hb2 = (c + 1u) * 805459861u;
  }
  const float* tb = tbl + ((size_t)l << 20);   // l * 2^19 entries * 2 floats
  float f0 = 0.f, f1 = 0.f;
  #pragma unroll
  for (int i = 0; i < 8; ++i) {
    unsigned h = ((i & 4) ? hb0 : ha0) ^ ((i & 2) ? hb1 : ha1) ^ ((i & 1) ? hb2 : ha2);
    float wt = ((i & 4) ? w0 : 1.f - w0) * ((i & 2) ? w1 : 1.f - w1) * ((i & 1) ? w2 : 1.f - w2);
    float2 fv = *(const float2*)(tb + 2u * (h & TMASK));
    f0 += wt * fv.x;
    f1 += wt * fv.y;
  }
  enc2[l * N + p] = (unsigned)f2bf(f0) | ((unsigned)f2bf(f1) << 16);
}

// ---------------------------------------------------------------------------
// Kernel B: fused MLP. Reads enc2 (level-major packed bf16).
// ---------------------------------------------------------------------------
__global__ __launch_bounds__(256, 2) void mlp_k(
    const float* __restrict__ dirs,
    const unsigned* __restrict__ enc2,
    const float* __restrict__ fw0, const float* __restrict__ fb0,
    const float* __restrict__ fw1, const float* __restrict__ fb1,
    const float* __restrict__ fw2, const float* __restrict__ fb2,
    const float* __restrict__ fw3, const float* __restrict__ fb3,
    const float* __restrict__ rw0, const float* __restrict__ rb0,
    const float* __restrict__ rw1, const float* __restrict__ rb1,
    const float* __restrict__ rw2, const float* __restrict__ rb2,
    float* __restrict__ outp, int Nrows, ResParams rp)
{
  __shared__ __align__(16) short Wlds[19584];
  __shared__ float Blds[272];
  __shared__ __align__(16) short Atile[4 * 16 * 104];

  const int tid  = threadIdx.x;
  const int wave = tid >> 6;
  const int lane = tid & 63;
  const int m    = lane & 15;
  const int quad = lane >> 4;
  const int row0 = blockIdx.x * 64 + wave * 16;
  short* At = Atile + wave * (16 * 104);

  stageW<48, 64, 64, 72>(fw0, Wlds + W0_OFF, tid);
  stageW<64, 64, 64, 72>(fw1, Wlds + W1_OFF, tid);
  stageW<64, 64, 64, 72>(fw2, Wlds + W2_OFF, tid);
  stageW<64, 65, 80, 72>(fw3, Wlds + W3_OFF, tid);
  stageB<64, 64>(fb0, Blds + 0,   tid);
  stageB<64, 64>(fb1, Blds + 64,  tid);
  stageB<64, 64>(fb2, Blds + 128, tid);
  stageB<65, 80>(fb3, Blds + 192, tid);

  // SH3 dirs at k=64..72, zeros k=48..63 / 73..103
  if (lane < 16) {
    int row = row0 + lane;
    float dx = dirs[row * 3 + 0];
    float dy = dirs[row * 3 + 1];
    float dz = dirs[row * 3 + 2];
    short8 z8 = {0, 0, 0, 0, 0, 0, 0, 0};
    short8 s07;
    s07[0] = (short)f2bf(0.28209479177387814f);
    s07[1] = (short)f2bf(-0.48860251190291987f * dy);
    s07[2] = (short)f2bf(0.48860251190291987f * dz);
    s07[3] = (short)f2bf(-0.48860251190291987f * dx);
    s07[4] = (short)f2bf(1.0925484305920792f * dx * dy);
    s07[5] = (short)f2bf(-1.0925484305920792f * dy * dz);
    s07[6] = (short)f2bf(0.31539156525252005f * (3.0f * dz * dz - 1.0f));
    s07[7] = (short)f2bf(-1.0925484305920792f * dx * dz);
    short8 s8v = {0, 0, 0, 0, 0, 0, 0, 0};
    s8v[0] = (short)f2bf(0.5462742152960396f * (dx * dx - dy * dy));
    short* rb = At + lane * 104;
    *(short8*)(rb + 48) = z8;
    *(short8*)(rb + 56) = z8;
    *(short8*)(rb + 64) = s07;
    *(short8*)(rb + 72) = s8v;
    *(short8*)(rb + 80) = z8;
    *(short8*)(rb + 88) = z8;
    *(short8*)(rb + 96) = z8;
  }

  // A-tile k=0..47 from enc2: 16-lane groups read one 64B line per level.
  for (int i = lane; i < 16 * LVL; i += 64) {
    int l = i >> 4;
    int r = i & 15;
    unsigned v = enc2[l * Nrows + row0 + r];
    *(unsigned*)(At + r * 104 + 2 * l) = v;
  }

  __syncthreads();

  floatx4 acc[5];

  // L0
  run_layer<2, 4, 72>(At, Wlds + W0_OFF, m, quad, acc);
  #pragma unroll
  for (int cb = 0; cb < 4; ++cb) {
    float bc = Blds[0 + cb * 16 + m];
    #pragma unroll
    for (int r = 0; r < 4; ++r) {
      float v = geluf(acc[cb][r] + bc);
      At[(quad * 4 + r) * 104 + cb * 16 + m] = (short)f2bf(v);
    }
  }
  // L1
  run_layer<2, 4, 72>(At, Wlds + W1_OFF, m, quad, acc);
  #pragma unroll
  for (int cb = 0; cb < 4; ++cb) {
    float bc = Blds[64 + cb * 16 + m];
    #pragma unroll
    for (int r = 0; r < 4; ++r) {
      float v = geluf(acc[cb][r] + bc);
      At[(quad * 4 + r) * 104 + cb * 16 + m] = (short)f2bf(v);
    }
  }
  // L2
  run_layer<2, 4, 72>(At, Wlds + W2_OFF, m, quad, acc);
  #pragma unroll
  for (int cb = 0; cb < 4; ++cb) {
    float bc = Blds[128 + cb * 16 + m];
    #pragma unroll
    for (int r = 0; r < 4; ++r) {
      float v = geluf(acc[cb][r] + bc);
      At[(quad * 4 + r) * 104 + cb * 16 + m] = (short)f2bf(v);
    }
  }
  // L3: col0 -> softplus -> density ; cols 1..64 -> gelu -> k=0..63
  run_layer<2, 5, 72>(At, Wlds + W3_OFF, m, quad, acc);
  #pragma unroll
  for (int cb = 0; cb < 5; ++cb) {
    int col = cb * 16 + m;
    float bc = Blds[192 + col];
    #pragma unroll
    for (int r = 0; r < 4; ++r) {
      float v = acc[cb][r] + bc;
      int row = quad * 4 + r;
      if (col == 0) {
        float d = (v > 15.f) ? v : log1pf(expf(v));
        outp[3 * Nrows + row0 + row] = d;
      } else if (col <= 64) {
        At[row * 104 + (col - 1)] = (short)f2bf(geluf(v));
      }
    }
  }

  __syncthreads();

  stageW<73, 64, 64, 104>(rw0, Wlds + R0_OFF, tid);
  stageW<64, 64, 64,  72>(rw1, Wlds + R1_OFF, tid);
  stageW<64,  3, 16,  72>(rw2, Wlds + R2_OFF, tid);
  stageB<64, 64>(rb0, Blds + 0,   tid);
  stageB<64, 64>(rb1, Blds + 64,  tid);
  stageB< 3, 16>(rb2, Blds + 128, tid);

  __syncthreads();

  // L4: [feat64 | sh9 | 0pad] (K=96) -> 64, gelu
  run_layer<3, 4, 104>(At, Wlds + R0_OFF, m, quad, acc);
  #pragma unroll
  for (int cb = 0; cb < 4; ++cb) {
    float bc = Blds[0 + cb * 16 + m];
    #pragma unroll
    for (int r = 0; r < 4; ++r) {
      float v = geluf(acc[cb][r] + bc);
      At[(quad * 4 + r) * 104 + cb * 16 + m] = (short)f2bf(v);
    }
  }
  // L5
  run_layer<2, 4, 72>(At, Wlds + R1_OFF, m, quad, acc);
  #pragma unroll
  for (int cb = 0; cb < 4; ++cb) {
    float bc = Blds[64 + cb * 16 + m];
    #pragma unroll
    for (int r = 0; r < 4; ++r) {
      float v = geluf(acc[cb][r] + bc);
      At[(quad * 4 + r) * 104 + cb * 16 + m] = (short)f2bf(v);
    }
  }
  // L6: 64 -> 3, sigmoid -> rgb
  run_layer<2, 1, 72>(At, Wlds + R2_OFF, m, quad, acc);
  {
    float bc = Blds[128 + m];
    #pragma unroll
    for (int r = 0; r < 4; ++r) {
      float v = acc[0][r] + bc;
      float s = 1.0f / (1.0f + expf(-v));
      if (m < 3) outp[(row0 + quad * 4 + r) * 3 + m] = s;
    }
  }
}

// ---------------------------------------------------------------------------
// Fallback: fully fused kernel (round-2 structure, f32-committed). Used only
// if ws_size can't hold enc2.
// ---------------------------------------------------------------------------
__global__ __launch_bounds__(256, 2) void nerf_fused(
    const float* __restrict__ pts,
    const float* __restrict__ dirs,
    const float* __restrict__ tbl,
    const float* __restrict__ fw0, const float* __restrict__ fb0,
    const float* __restrict__ fw1, const float* __restrict__ fb1,
    const float* __restrict__ fw2, const float* __restrict__ fb2,
    const float* __restrict__ fw3, const float* __restrict__ fb3,
    const float* __restrict__ rw0, const float* __restrict__ rb0,
    const float* __restrict__ rw1, const float* __restrict__ rb1,
    const float* __restrict__ rw2, const float* __restrict__ rb2,
    float* __restrict__ outp, int Nrows, ResParams rp)
{
  __shared__ __align__(16) short Wlds[19584];
  __shared__ float Blds[272];
  __shared__ __align__(16) short Atile[4 * 16 * 104];

  const int tid  = threadIdx.x;
  const int wave = tid >> 6;
  const int lane = tid & 63;
  const int m    = lane & 15;
  const int quad = lane >> 4;
  const int row0 = blockIdx.x * 64 + wave * 16;
  short* At = Atile + wave * (16 * 104);

  stageW<48, 64, 64, 72>(fw0, Wlds + W0_OFF, tid);
  stageW<64, 64, 64, 72>(fw1, Wlds + W1_OFF, tid);
  stageW<64, 64, 64, 72>(fw2, Wlds + W2_OFF, tid);
  stageW<64, 65, 80, 72>(fw3, Wlds + W3_OFF, tid);
  stageB<64, 64>(fb0, Blds + 0,   tid);
  stageB<64, 64>(fb1, Blds + 64,  tid);
  stageB<64, 64>(fb2, Blds + 128, tid);
  stageB<65, 80>(fb3, Blds + 192, tid);

  if (lane < 16) {
    int row = row0 + lane;
    float dx = dirs[row * 3 + 0];
    float dy = dirs[row * 3 + 1];
    float dz = dirs[row * 3 + 2];
    short8 z8 = {0, 0, 0, 0, 0, 0, 0, 0};
    short8 s07;
    s07[0] = (short)f2bf(0.28209479177387814f);
    s07[1] = (short)f2bf(-0.48860251190291987f * dy);
    s07[2] = (short)f2bf(0.48860251190291987f * dz);
    s07[3] = (short)f2bf(-0.48860251190291987f * dx);
    s07[4] = (short)f2bf(1.0925484305920792f * dx * dy);
    s07[5] = (short)f2bf(-1.0925484305920792f * dy * dz);
    s07[6] = (short)f2bf(0.31539156525252005f * (3.0f * dz * dz - 1.0f));
    s07[7] = (short)f2bf(-1.0925484305920792f * dx * dz);
    short8 s8v = {0, 0, 0, 0, 0, 0, 0, 0};
    s8v[0] = (short)f2bf(0.5462742152960396f * (dx * dx - dy * dy));
    short* rb = At + lane * 104;
    *(short8*)(rb + 48) = z8;
    *(short8*)(rb + 56) = z8;
    *(short8*)(rb + 64) = s07;
    *(short8*)(rb + 72) = s8v;
    *(short8*)(rb + 80) = z8;
    *(short8*)(rb + 88) = z8;
    *(short8*)(rb + 96) = z8;
  }

  for (int t = lane; t < 16 * LVL; t += 64) {
    int r = t / LVL;
    int l = t - r * LVL;
    int row = row0 + r;
    float res = rp.r[l];
    float w0, w1, w2;
    unsigned ha0, hb0, ha1, hb1, ha2, hb2;
    {
      float x  = (pts[row * 3 + 0] + 1.0f) * 0.5f;
      float po = x * res;
      float fl = floorf(po);
      w0 = po - fl;
      unsigned c = (unsigned)fl;
      ha0 = c; hb0 = c + 1u;
    }
    {
      float x  = (pts[row * 3 + 1] + 1.0f) * 0.5f;
      float po = x * res;
      float fl = floorf(po);
      w1 = po - fl;
      unsigned c = (unsigned)fl;
      ha1 = c * 2654435761u; hb1 = (c + 1u) * 2654435761u;
    }
    {
      float x  = (pts[row * 3 + 2] + 1.0f) * 0.5f;
      float po = x * res;
      float fl = floorf(po);
      w2 = po - fl;
      unsigned c = (unsigned)fl;
      ha2 = c * 805459861u; hb2 = (c + 1u) * 805459861u;
    }
    const float* tb = tbl + ((size_t)l << 20);
    float f0 = 0.f, f1 = 0.f;
    #pragma unroll
    for (int i = 0; i < 8; ++i) {
      unsigned h = ((i & 4) ? hb0 : ha0) ^ ((i & 2) ? hb1 : ha1) ^ ((i & 1) ? hb2 : ha2);
      float wt = ((i & 4) ? w0 : 1.f - w0) * ((i & 2) ? w1 : 1.f - w1) * ((i & 1) ? w2 : 1.f - w2);
      float2 fv = *(const float2*)(tb + 2u * (h & TMASK));
      f0 += wt * fv.x;
      f1 += wt * fv.y;
    }
    unsigned pk = (unsigned)f2bf(f0) | ((unsigned)f2bf(f1) << 16);
    *(unsigned*)(At + r * 104 + 2 * l) = pk;
  }

  __syncthreads();

  floatx4 acc[5];

  run_layer<2, 4, 72>(At, Wlds + W0_OFF, m, quad, acc);
  #pragma unroll
  for (int cb = 0; cb < 4; ++cb) {
    float bc = Blds[0 + cb * 16 + m];
    #pragma unroll
    for (int r = 0; r < 4; ++r) {
      float v = geluf(acc[cb][r] + bc);
      At[(quad * 4 + r) * 104 + cb * 16 + m] = (short)f2bf(v);
    }
  }
  run_layer<2, 4, 72>(At, Wlds + W1_OFF, m, quad, acc);
  #pragma unroll
  for (int cb = 0; cb < 4; ++cb) {
    float bc = Blds[64 + cb * 16 + m];
    #pragma unroll
    for (int r = 0; r < 4; ++r) {
      float v = geluf(acc[cb][r] + bc);
      At[(quad * 4 + r) * 104 + cb * 16 + m] = (short)f2bf(v);
    }
  }
  run_layer<2, 4, 72>(At, Wlds + W2_OFF, m, quad, acc);
  #pragma unroll
  for (int cb = 0; cb < 4; ++cb) {
    float bc = Blds[128 + cb * 16 + m];
    #pragma unroll
    for (int r = 0; r < 4; ++r) {
      float v = geluf(acc[cb][r] + bc);
      At[(quad * 4 + r) * 104 + cb * 16 + m] = (short)f2bf(v);
    }
  }
  run_layer<2, 5, 72>(At, Wlds + W3_OFF, m, quad, acc);
  #pragma unroll
  for (int cb = 0; cb < 5; ++cb) {
    int col = cb * 16 + m;
    float bc = Blds[192 + col];
    #pragma unroll
    for (int r = 0; r < 4; ++r) {
      float v = acc[cb][r] + bc;
      int row = quad * 4 + r;
      if (col == 0) {
        float d = (v > 15.f) ? v : log1pf(expf(v));
        outp[3 * Nrows + row0 + row] = d;
      } else if (col <= 64) {
        At[row * 104 + (col - 1)] = (short)f2bf(geluf(v));
      }
    }
  }

  __syncthreads();

  stageW<73, 64, 64, 104>(rw0, Wlds + R0_OFF, tid);
  stageW<64, 64, 64,  72>(rw1, Wlds + R1_OFF, tid);
  stageW<64,  3, 16,  72>(rw2, Wlds + R2_OFF, tid);
  stageB<64, 64>(rb0, Blds + 0,   tid);
  stageB<64, 64>(rb1, Blds + 64,  tid);
  stageB< 3, 16>(rb2, Blds + 128, tid);

  __syncthreads();

  run_layer<3, 4, 104>(At, Wlds + R0_OFF, m, quad, acc);
  #pragma unroll
  for (int cb = 0; cb < 4; ++cb) {
    float bc = Blds[0 + cb * 16 + m];
    #pragma unroll
    for (int r = 0; r < 4; ++r) {
      float v = geluf(acc[cb][r] + bc);
      At[(quad * 4 + r) * 104 + cb * 16 + m] = (short)f2bf(v);
    }
  }
  run_layer<2, 4, 72>(At, Wlds + R1_OFF, m, quad, acc);
  #pragma unroll
  for (int cb = 0; cb < 4; ++cb) {
    float bc = Blds[64 + cb * 16 + m];
    #pragma unroll
    for (int r = 0; r < 4; ++r) {
      float v = geluf(acc[cb][r] + bc);
      At[(quad * 4 + r) * 104 + cb * 16 + m] = (short)f2bf(v);
    }
  }
  run_layer<2, 1, 72>(At, Wlds + R2_OFF, m, quad, acc);
  {
    float bc = Blds[128 + m];
    #pragma unroll
    for (int r = 0; r < 4; ++r) {
      float v = acc[0][r] + bc;
      float s = 1.0f / (1.0f + expf(-v));
      if (m < 3) outp[(row0 + quad * 4 + r) * 3 + m] = s;
    }
  }
}

extern "C" void kernel_launch(void* const* d_in, const int* in_sizes, int n_in,
                              void* d_out, int out_size, void* d_ws, size_t ws_size,
                              hipStream_t stream) {
  ResParams rp;
  double b = exp((log(2048.0) - log(16.0)) / 23.0);
  for (int l = 0; l < LVL; ++l) rp.r[l] = (float)floor(16.0 * pow(b, (double)l));

  const float* pts  = (const float*)d_in[0];
  const float* dirs = (const float*)d_in[1];
  const float* tbl  = (const float*)d_in[2];
  float* outp = (float*)d_out;

  int n = in_sizes[0] / 3;            // 524288
  int mlp_blocks = n / 64;            // 8192
  size_t enc_bytes = (size_t)LVL * (size_t)n * 4u;

  if (ws_size >= enc_bytes) {
    unsigned* enc2 = (unsigned*)d_ws;
    int enc_blocks = LVL * (n / 256);  // level-major: 2048 blocks/level
    hash_encode_k<<<enc_blocks, 256, 0, stream>>>(pts, tbl, enc2, n, rp);
    mlp_k<<<mlp_blocks, 256, 0, stream>>>(
        dirs, enc2,
        (const float*)d_in[3],  (const float*)d_in[4],
        (const float*)d_in[5],  (const float*)d_in[6],
        (const float*)d_in[7],  (const float*)d_in[8],
        (const float*)d_in[9],  (const float*)d_in[10],
        (const float*)d_in[11], (const float*)d_in[12],
        (const float*)d_in[13], (const float*)d_in[14],
        (const float*)d_in[15], (const float*)d_in[16],
        outp, n, rp);
  } else {
    nerf_fused<<<mlp_blocks, 256, 0, stream>>>(
        pts, dirs, tbl,
        (const float*)d_in[3],  (const float*)d_in[4],
        (const float*)d_in[5],  (const float*)d_in[6],
        (const float*)d_in[7],  (const float*)d_in[8],
        (const float*)d_in[9],  (const float*)d_in[10],
        (const float*)d_in[11], (const float*)d_in[12],
        (const float*)d_in[13], (const float*)d_in[14],
        (const float*)d_in[15], (const float*)d_in[16],
        outp, n, rp);
  }
}

// Round 4
// 697.145 us; speedup vs baseline: 1.8286x; 1.3862x over previous
//
#include <hip/hip_runtime.h>
#include <math.h>

#define LVL 24
#define TMASK ((1u << 19) - 1u)

typedef short short8 __attribute__((ext_vector_type(8)));
typedef float floatx4 __attribute__((ext_vector_type(4)));

struct ResParams { float r[LVL]; };

__device__ __forceinline__ unsigned short f2bf(float f) {
  union { float f; unsigned u; } t; t.f = f;
  unsigned u = t.u;
  u += 0x7FFFu + ((u >> 16) & 1u);   // RNE
  return (unsigned short)(u >> 16);
}
// Fast exact-form gelu: A&S 7.1.26 erf, |err| < 1.5e-7, branch-free.
__device__ __forceinline__ float geluf(float x) {
  float a = fabsf(x) * 0.7071067811865476f;
  float t = __builtin_amdgcn_rcpf(fmaf(0.3275911f, a, 1.0f));
  float p = fmaf(t, 1.061405429f, -1.453152027f);
  p = fmaf(t, p, 1.421413741f);
  p = fmaf(t, p, -0.284496736f);
  p = fmaf(t, p, 0.254829592f);
  float er = 1.0f - p * t * __expf(-a * a);
  return 0.5f * x * (1.0f + copysignf(er, x));
}
__device__ __forceinline__ floatx4 mfma16(short8 a, short8 b, floatx4 c) {
  return __builtin_amdgcn_mfma_f32_16x16x32_bf16(a, b, c, 0, 0, 0);
}

// LDS weight offsets (shorts). Stage1: fw0..fw3. Stage2 (reuse): rw0..rw2.
#define W0_OFF 0
#define W1_OFF 4608
#define W2_OFF 9216
#define W3_OFF 13824   // 80 rows x 72
#define S1_SHORTS 19584
#define R0_OFF 0       // 64 rows x 104
#define R1_OFF 6656
#define R2_OFF 11264   // 16 rows x 72
#define S2_SHORTS 12416

template<int K, int NOUT, int NROWS, int STRIDE>
__device__ void stageW(const float* w, short* dst, int tid) {
  for (int i = tid; i < NROWS * STRIDE; i += 256) {
    int n = i / STRIDE;
    int k = i - n * STRIDE;
    short v = 0;
    if (n < NOUT && k < K) v = (short)f2bf(w[k * NOUT + n]);
    dst[i] = v;
  }
}
template<int NOUT, int NPAD>
__device__ void stageB(const float* b, float* dst, int tid) {
  for (int i = tid; i < NPAD; i += 256) dst[i] = (i < NOUT) ? b[i] : 0.0f;
}

template<int KCH, int CBS, int WSTRIDE>
__device__ __forceinline__ void run_layer(const short* At, const short* Wb,
                                          int m, int quad, floatx4* acc) {
  #pragma unroll
  for (int cb = 0; cb < CBS; ++cb) acc[cb] = (floatx4){0.f, 0.f, 0.f, 0.f};
  #pragma unroll
  for (int c = 0; c < KCH; ++c) {
    short8 a = *(const short8*)(At + m * 104 + c * 32 + quad * 8);
    #pragma unroll
    for (int cb = 0; cb < CBS; ++cb) {
      short8 b = *(const short8*)(Wb + (cb * 16 + m) * WSTRIDE + c * 32 + quad * 8);
      acc[cb] = mfma16(a, b, acc[cb]);
    }
  }
}

// ---------------------------------------------------------------------------
// Prep kernel: build bf16 weight images (transposed, padded, exact LDS layout)
// + padded f32 bias images in workspace. 8 blocks, ~3 us.
// ---------------------------------------------------------------------------
__device__ void prepW(const float* w, short* dst, int K, int NOUT, int NROWS, int STRIDE) {
  for (int i = threadIdx.x; i < NROWS * STRIDE; i += 256) {
    int n = i / STRIDE;
    int k = i - n * STRIDE;
    short v = 0;
    if (n < NOUT && k < K) v = (short)f2bf(w[k * NOUT + n]);
    dst[i] = v;
  }
}
__global__ __launch_bounds__(256) void prep_weights(
    const float* __restrict__ fw0, const float* __restrict__ fb0,
    const float* __restrict__ fw1, const float* __restrict__ fb1,
    const float* __restrict__ fw2, const float* __restrict__ fb2,
    const float* __restrict__ fw3, const float* __restrict__ fb3,
    const float* __restrict__ rw0, const float* __restrict__ rb0,
    const float* __restrict__ rw1, const float* __restrict__ rb1,
    const float* __restrict__ rw2, const float* __restrict__ rb2,
    short* __restrict__ Wimg1, short* __restrict__ Wimg2,
    float* __restrict__ Bimg1, float* __restrict__ Bimg2)
{
  int b = blockIdx.x;
  int tid = threadIdx.x;
  switch (b) {
    case 0: prepW(fw0, Wimg1 + W0_OFF, 48, 64, 64, 72); break;
    case 1: prepW(fw1, Wimg1 + W1_OFF, 64, 64, 64, 72); break;
    case 2: prepW(fw2, Wimg1 + W2_OFF, 64, 64, 64, 72); break;
    case 3: prepW(fw3, Wimg1 + W3_OFF, 64, 65, 80, 72); break;
    case 4: prepW(rw0, Wimg2 + R0_OFF, 73, 64, 64, 104); break;
    case 5: prepW(rw1, Wimg2 + R1_OFF, 64, 64, 64, 72); break;
    case 6: prepW(rw2, Wimg2 + R2_OFF, 64, 3, 16, 72); break;
    case 7:
      if (tid < 64) {
        Bimg1[tid]       = fb0[tid];
        Bimg1[64 + tid]  = fb1[tid];
        Bimg1[128 + tid] = fb2[tid];
        Bimg2[tid]       = rb0[tid];
        Bimg2[64 + tid]  = rb1[tid];
      }
      if (tid < 80) Bimg1[192 + tid] = (tid < 65) ? fb3[tid] : 0.0f;
      if (tid < 16) Bimg2[128 + tid] = (tid < 3) ? rb2[tid] : 0.0f;
      break;
  }
}

// ---------------------------------------------------------------------------
// Kernel A: hash-grid encode. One thread per (level, point), level-major grid.
// ---------------------------------------------------------------------------
__global__ __launch_bounds__(256) void hash_encode_k(
    const float* __restrict__ pts, const float* __restrict__ tbl,
    unsigned* __restrict__ enc2, int N, ResParams rp)
{
  int bid = blockIdx.x;
  int l   = bid >> 11;                       // 2048 blocks per level
  int p   = ((bid & 2047) << 8) + threadIdx.x;
  float res = rp.r[l];

  float w0, w1, w2;
  unsigned ha0, hb0, ha1, hb1, ha2, hb2;
  {
    float x  = (pts[p * 3 + 0] + 1.0f) * 0.5f;
    float po = x * res;
    float fl = floorf(po);
    w0 = po - fl;
    unsigned c = (unsigned)fl;
    ha0 = c; hb0 = c + 1u;
  }
  {
    float x  = (pts[p * 3 + 1] + 1.0f) * 0.5f;
    float po = x * res;
    float fl = floorf(po);
    w1 = po - fl;
    unsigned c = (unsigned)fl;
    ha1 = c * 2654435761u; hb1 = (c + 1u) * 2654435761u;
  }
  {
    float x  = (pts[p * 3 + 2] + 1.0f) * 0.5f;
    float po = x * res;
    float fl = floorf(po);
    w2 = po - fl;
    unsigned c = (unsigned)fl;
    ha2 = c * 805459861u; hb2 = (c + 1u) * 805459861u;
  }
  const float* tb = tbl + ((size_t)l << 20);   // l * 2^19 entries * 2 floats
  float f0 = 0.f, f1 = 0.f;
  #pragma unroll
  for (int i = 0; i < 8; ++i) {
    unsigned h = ((i & 4) ? hb0 : ha0) ^ ((i & 2) ? hb1 : ha1) ^ ((i & 1) ? hb2 : ha2);
    float wt = ((i & 4) ? w0 : 1.f - w0) * ((i & 2) ? w1 : 1.f - w1) * ((i & 1) ? w2 : 1.f - w2);
    float2 fv = *(const float2*)(tb + 2u * (h & TMASK));
    f0 += wt * fv.x;
    f1 += wt * fv.y;
  }
  enc2[l * N + p] = (unsigned)f2bf(f0) | ((unsigned)f2bf(f1) << 16);
}

// ---------------------------------------------------------------------------
// Kernel B: fused MLP. PREP=true stages pre-built images with b128 copies.
// ---------------------------------------------------------------------------
template<bool PREP>
__global__ __launch_bounds__(256, 2) void mlp_k(
    const float* __restrict__ dirs,
    const unsigned* __restrict__ enc2,
    const float* __restrict__ fw0, const float* __restrict__ fb0,
    const float* __restrict__ fw1, const float* __restrict__ fb1,
    const float* __restrict__ fw2, const float* __restrict__ fb2,
    const float* __restrict__ fw3, const float* __restrict__ fb3,
    const float* __restrict__ rw0, const float* __restrict__ rb0,
    const float* __restrict__ rw1, const float* __restrict__ rb1,
    const float* __restrict__ rw2, const float* __restrict__ rb2,
    const short* __restrict__ Wimg1, const short* __restrict__ Wimg2,
    const float* __restrict__ Bimg1, const float* __restrict__ Bimg2,
    float* __restrict__ outp, int Nrows)
{
  __shared__ __align__(16) short Wlds[19584];
  __shared__ __align__(16) float Blds[272];
  __shared__ __align__(16) short Atile[4 * 16 * 104];

  const int tid  = threadIdx.x;
  const int wave = tid >> 6;
  const int lane = tid & 63;
  const int m    = lane & 15;
  const int quad = lane >> 4;
  const int row0 = blockIdx.x * 64 + wave * 16;
  short* At = Atile + wave * (16 * 104);

  if constexpr (PREP) {
    for (int i = tid; i < S1_SHORTS / 8; i += 256)
      ((short8*)Wlds)[i] = ((const short8*)Wimg1)[i];
    if (tid < 68) ((float4*)Blds)[tid] = ((const float4*)Bimg1)[tid];
  } else {
    stageW<48, 64, 64, 72>(fw0, Wlds + W0_OFF, tid);
    stageW<64, 64, 64, 72>(fw1, Wlds + W1_OFF, tid);
    stageW<64, 64, 64, 72>(fw2, Wlds + W2_OFF, tid);
    stageW<64, 65, 80, 72>(fw3, Wlds + W3_OFF, tid);
    stageB<64, 64>(fb0, Blds + 0,   tid);
    stageB<64, 64>(fb1, Blds + 64,  tid);
    stageB<64, 64>(fb2, Blds + 128, tid);
    stageB<65, 80>(fb3, Blds + 192, tid);
  }

  // SH3 dirs at k=64..72, zeros k=48..63 / 73..103
  if (lane < 16) {
    int row = row0 + lane;
    float dx = dirs[row * 3 + 0];
    float dy = dirs[row * 3 + 1];
    float dz = dirs[row * 3 + 2];
    short8 z8 = {0, 0, 0, 0, 0, 0, 0, 0};
    short8 s07;
    s07[0] = (short)f2bf(0.28209479177387814f);
    s07[1] = (short)f2bf(-0.48860251190291987f * dy);
    s07[2] = (short)f2bf(0.48860251190291987f * dz);
    s07[3] = (short)f2bf(-0.48860251190291987f * dx);
    s07[4] = (short)f2bf(1.0925484305920792f * dx * dy);
    s07[5] = (short)f2bf(-1.0925484305920792f * dy * dz);
    s07[6] = (short)f2bf(0.31539156525252005f * (3.0f * dz * dz - 1.0f));
    s07[7] = (short)f2bf(-1.0925484305920792f * dx * dz);
    short8 s8v = {0, 0, 0, 0, 0, 0, 0, 0};
    s8v[0] = (short)f2bf(0.5462742152960396f * (dx * dx - dy * dy));
    short* rb = At + lane * 104;
    *(short8*)(rb + 48) = z8;
    *(short8*)(rb + 56) = z8;
    *(short8*)(rb + 64) = s07;
    *(short8*)(rb + 72) = s8v;
    *(short8*)(rb + 80) = z8;
    *(short8*)(rb + 88) = z8;
    *(short8*)(rb + 96) = z8;
  }

  // A-tile k=0..47 from enc2
  for (int i = lane; i < 16 * LVL; i += 64) {
    int l = i >> 4;
    int r = i & 15;
    unsigned v = enc2[l * Nrows + row0 + r];
    *(unsigned*)(At + r * 104 + 2 * l) = v;
  }

  __syncthreads();

  floatx4 acc[5];

  // L0
  run_layer<2, 4, 72>(At, Wlds + W0_OFF, m, quad, acc);
  #pragma unroll
  for (int cb = 0; cb < 4; ++cb) {
    float bc = Blds[0 + cb * 16 + m];
    #pragma unroll
    for (int r = 0; r < 4; ++r) {
      float v = geluf(acc[cb][r] + bc);
      At[(quad * 4 + r) * 104 + cb * 16 + m] = (short)f2bf(v);
    }
  }
  // L1
  run_layer<2, 4, 72>(At, Wlds + W1_OFF, m, quad, acc);
  #pragma unroll
  for (int cb = 0; cb < 4; ++cb) {
    float bc = Blds[64 + cb * 16 + m];
    #pragma unroll
    for (int r = 0; r < 4; ++r) {
      float v = geluf(acc[cb][r] + bc);
      At[(quad * 4 + r) * 104 + cb * 16 + m] = (short)f2bf(v);
    }
  }
  // L2
  run_layer<2, 4, 72>(At, Wlds + W2_OFF, m, quad, acc);
  #pragma unroll
  for (int cb = 0; cb < 4; ++cb) {
    float bc = Blds[128 + cb * 16 + m];
    #pragma unroll
    for (int r = 0; r < 4; ++r) {
      float v = geluf(acc[cb][r] + bc);
      At[(quad * 4 + r) * 104 + cb * 16 + m] = (short)f2bf(v);
    }
  }
  // L3: col0 -> softplus -> density ; cols 1..64 -> gelu -> k=0..63
  run_layer<2, 5, 72>(At, Wlds + W3_OFF, m, quad, acc);
  #pragma unroll
  for (int cb = 0; cb < 5; ++cb) {
    int col = cb * 16 + m;
    float bc = Blds[192 + col];
    #pragma unroll
    for (int r = 0; r < 4; ++r) {
      float v = acc[cb][r] + bc;
      int row = quad * 4 + r;
      if (col == 0) {
        float d = (v > 15.f) ? v : __logf(1.0f + __expf(v));
        outp[3 * Nrows + row0 + row] = d;
      } else if (col <= 64) {
        At[row * 104 + (col - 1)] = (short)f2bf(geluf(v));
      }
    }
  }

  __syncthreads();

  if constexpr (PREP) {
    for (int i = tid; i < S2_SHORTS / 8; i += 256)
      ((short8*)Wlds)[i] = ((const short8*)Wimg2)[i];
    if (tid < 36) ((float4*)Blds)[tid] = ((const float4*)Bimg2)[tid];
  } else {
    stageW<73, 64, 64, 104>(rw0, Wlds + R0_OFF, tid);
    stageW<64, 64, 64,  72>(rw1, Wlds + R1_OFF, tid);
    stageW<64,  3, 16,  72>(rw2, Wlds + R2_OFF, tid);
    stageB<64, 64>(rb0, Blds + 0,   tid);
    stageB<64, 64>(rb1, Blds + 64,  tid);
    stageB< 3, 16>(rb2, Blds + 128, tid);
  }

  __syncthreads();

  // L4: [feat64 | sh9 | 0pad] (K=96) -> 64, gelu
  run_layer<3, 4, 104>(At, Wlds + R0_OFF, m, quad, acc);
  #pragma unroll
  for (int cb = 0; cb < 4; ++cb) {
    float bc = Blds[0 + cb * 16 + m];
    #pragma unroll
    for (int r = 0; r < 4; ++r) {
      float v = geluf(acc[cb][r] + bc);
      At[(quad * 4 + r) * 104 + cb * 16 + m] = (short)f2bf(v);
    }
  }
  // L5
  run_layer<2, 4, 72>(At, Wlds + R1_OFF, m, quad, acc);
  #pragma unroll
  for (int cb = 0; cb < 4; ++cb) {
    float bc = Blds[64 + cb * 16 + m];
    #pragma unroll
    for (int r = 0; r < 4; ++r) {
      float v = geluf(acc[cb][r] + bc);
      At[(quad * 4 + r) * 104 + cb * 16 + m] = (short)f2bf(v);
    }
  }
  // L6: 64 -> 3, sigmoid -> rgb
  run_layer<2, 1, 72>(At, Wlds + R2_OFF, m, quad, acc);
  {
    float bc = Blds[128 + m];
    #pragma unroll
    for (int r = 0; r < 4; ++r) {
      float v = acc[0][r] + bc;
      float s = __builtin_amdgcn_rcpf(1.0f + __expf(-v));
      if (m < 3) outp[(row0 + quad * 4 + r) * 3 + m] = s;
    }
  }
}

// ---------------------------------------------------------------------------
// Fallback: fully fused kernel (used only if ws too small for enc2).
// ---------------------------------------------------------------------------
__global__ __launch_bounds__(256, 2) void nerf_fused(
    const float* __restrict__ pts,
    const float* __restrict__ dirs,
    const float* __restrict__ tbl,
    const float* __restrict__ fw0, const float* __restrict__ fb0,
    const float* __restrict__ fw1, const float* __restrict__ fb1,
    const float* __restrict__ fw2, const float* __restrict__ fb2,
    const float* __restrict__ fw3, const float* __restrict__ fb3,
    const float* __restrict__ rw0, const float* __restrict__ rb0,
    const float* __restrict__ rw1, const float* __restrict__ rb1,
    const float* __restrict__ rw2, const float* __restrict__ rb2,
    float* __restrict__ outp, int Nrows, ResParams rp)
{
  __shared__ __align__(16) short Wlds[19584];
  __shared__ __align__(16) float Blds[272];
  __shared__ __align__(16) short Atile[4 * 16 * 104];

  const int tid  = threadIdx.x;
  const int wave = tid >> 6;
  const int lane = tid & 63;
  const int m    = lane & 15;
  const int quad = lane >> 4;
  const int row0 = blockIdx.x * 64 + wave * 16;
  short* At = Atile + wave * (16 * 104);

  stageW<48, 64, 64, 72>(fw0, Wlds + W0_OFF, tid);
  stageW<64, 64, 64, 72>(fw1, Wlds + W1_OFF, tid);
  stageW<64, 64, 64, 72>(fw2, Wlds + W2_OFF, tid);
  stageW<64, 65, 80, 72>(fw3, Wlds + W3_OFF, tid);
  stageB<64, 64>(fb0, Blds + 0,   tid);
  stageB<64, 64>(fb1, Blds + 64,  tid);
  stageB<64, 64>(fb2, Blds + 128, tid);
  stageB<65, 80>(fb3, Blds + 192, tid);

  if (lane < 16) {
    int row = row0 + lane;
    float dx = dirs[row * 3 + 0];
    float dy = dirs[row * 3 + 1];
    float dz = dirs[row * 3 + 2];
    short8 z8 = {0, 0, 0, 0, 0, 0, 0, 0};
    short8 s07;
    s07[0] = (short)f2bf(0.28209479177387814f);
    s07[1] = (short)f2bf(-0.48860251190291987f * dy);
    s07[2] = (short)f2bf(0.48860251190291987f * dz);
    s07[3] = (short)f2bf(-0.48860251190291987f * dx);
    s07[4] = (short)f2bf(1.0925484305920792f * dx * dy);
    s07[5] = (short)f2bf(-1.0925484305920792f * dy * dz);
    s07[6] = (short)f2bf(0.31539156525252005f * (3.0f * dz * dz - 1.0f));
    s07[7] = (short)f2bf(-1.0925484305920792f * dx * dz);
    short8 s8v = {0, 0, 0, 0, 0, 0, 0, 0};
    s8v[0] = (short)f2bf(0.5462742152960396f * (dx * dx - dy * dy));
    short* rb = At + lane * 104;
    *(short8*)(rb + 48) = z8;
    *(short8*)(rb + 56) = z8;
    *(short8*)(rb + 64) = s07;
    *(short8*)(rb + 72) = s8v;
    *(short8*)(rb + 80) = z8;
    *(short8*)(rb + 88) = z8;
    *(short8*)(rb + 96) = z8;
  }

  for (int t = lane; t < 16 * LVL; t += 64) {
    int r = t / LVL;
    int l = t - r * LVL;
    int row = row0 + r;
    float res = rp.r[l];
    float w0, w1, w2;
    unsigned ha0, hb0, ha1, hb1, ha2, hb2;
    {
      float x  = (pts[row * 3 + 0] + 1.0f) * 0.5f;
      float po = x * res;
      float fl = floorf(po);
      w0 = po - fl;
      unsigned c = (unsigned)fl;
      ha0 = c; hb0 = c + 1u;
    }
    {
      float x  = (pts[row * 3 + 1] + 1.0f) * 0.5f;
      float po = x * res;
      float fl = floorf(po);
      w1 = po - fl;
      unsigned c = (unsigned)fl;
      ha1 = c * 2654435761u; hb1 = (c + 1u) * 2654435761u;
    }
    {
      float x  = (pts[row * 3 + 2] + 1.0f) * 0.5f;
      float po = x * res;
      float fl = floorf(po);
      w2 = po - fl;
      unsigned c = (unsigned)fl;
      ha2 = c * 805459861u; hb2 = (c + 1u) * 805459861u;
    }
    const float* tb = tbl + ((size_t)l << 20);
    float f0 = 0.f, f1 = 0.f;
    #pragma unroll
    for (int i = 0; i < 8; ++i) {
      unsigned h = ((i & 4) ? hb0 : ha0) ^ ((i & 2) ? hb1 : ha1) ^ ((i & 1) ? hb2 : ha2);
      float wt = ((i & 4) ? w0 : 1.f - w0) * ((i & 2) ? w1 : 1.f - w1) * ((i & 1) ? w2 : 1.f - w2);
      float2 fv = *(const float2*)(tb + 2u * (h & TMASK));
      f0 += wt * fv.x;
      f1 += wt * fv.y;
    }
    unsigned pk = (unsigned)f2bf(f0) | ((unsigned)f2bf(f1) << 16);
    *(unsigned*)(At + r * 104 + 2 * l) = pk;
  }

  __syncthreads();

  floatx4 acc[5];

  run_layer<2, 4, 72>(At, Wlds + W0_OFF, m, quad, acc);
  #pragma unroll
  for (int cb = 0; cb < 4; ++cb) {
    float bc = Blds[0 + cb * 16 + m];
    #pragma unroll
    for (int r = 0; r < 4; ++r) {
      float v = geluf(acc[cb][r] + bc);
      At[(quad * 4 + r) * 104 + cb * 16 + m] = (short)f2bf(v);
    }
  }
  run_layer<2, 4, 72>(At, Wlds + W1_OFF, m, quad, acc);
  #pragma unroll
  for (int cb = 0; cb < 4; ++cb) {
    float bc = Blds[64 + cb * 16 + m];
    #pragma unroll
    for (int r = 0; r < 4; ++r) {
      float v = geluf(acc[cb][r] + bc);
      At[(quad * 4 + r) * 104 + cb * 16 + m] = (short)f2bf(v);
    }
  }
  run_layer<2, 4, 72>(At, Wlds + W2_OFF, m, quad, acc);
  #pragma unroll
  for (int cb = 0; cb < 4; ++cb) {
    float bc = Blds[128 + cb * 16 + m];
    #pragma unroll
    for (int r = 0; r < 4; ++r) {
      float v = geluf(acc[cb][r] + bc);
      At[(quad * 4 + r) * 104 + cb * 16 + m] = (short)f2bf(v);
    }
  }
  run_layer<2, 5, 72>(At, Wlds + W3_OFF, m, quad, acc);
  #pragma unroll
  for (int cb = 0; cb < 5; ++cb) {
    int col = cb * 16 + m;
    float bc = Blds[192 + col];
    #pragma unroll
    for (int r = 0; r < 4; ++r) {
      float v = acc[cb][r] + bc;
      int row = quad * 4 + r;
      if (col == 0) {
        float d = (v > 15.f) ? v : __logf(1.0f + __expf(v));
        outp[3 * Nrows + row0 + row] = d;
      } else if (col <= 64) {
        At[row * 104 + (col - 1)] = (short)f2bf(geluf(v));
      }
    }
  }

  __syncthreads();

  stageW<73, 64, 64, 104>(rw0, Wlds + R0_OFF, tid);
  stageW<64, 64, 64,  72>(rw1, Wlds + R1_OFF, tid);
  stageW<64,  3, 16,  72>(rw2, Wlds + R2_OFF, tid);
  stageB<64, 64>(rb0, Blds + 0,   tid);
  stageB<64, 64>(rb1, Blds + 64,  tid);
  stageB< 3, 16>(rb2, Blds + 128, tid);

  __syncthreads();

  run_layer<3, 4, 104>(At, Wlds + R0_OFF, m, quad, acc);
  #pragma unroll
  for (int cb = 0; cb < 4; ++cb) {
    float bc = Blds[0 + cb * 16 + m];
    #pragma unroll
    for (int r = 0; r < 4; ++r) {
      float v = geluf(acc[cb][r] + bc);
      At[(quad * 4 + r) * 104 + cb * 16 + m] = (short)f2bf(v);
    }
  }
  run_layer<2, 4, 72>(At, Wlds + R1_OFF, m, quad, acc);
  #pragma unroll
  for (int cb = 0; cb < 4; ++cb) {
    float bc = Blds[64 + cb * 16 + m];
    #pragma unroll
    for (int r = 0; r < 4; ++r) {
      float v = geluf(acc[cb][r] + bc);
      At[(quad * 4 + r) * 104 + cb * 16 + m] = (short)f2bf(v);
    }
  }
  run_layer<2, 1, 72>(At, Wlds + R2_OFF, m, quad, acc);
  {
    float bc = Blds[128 + m];
    #pragma unroll
    for (int r = 0; r < 4; ++r) {
      float v = acc[0][r] + bc;
      float s = __builtin_amdgcn_rcpf(1.0f + __expf(-v));
      if (m < 3) outp[(row0 + quad * 4 + r) * 3 + m] = s;
    }
  }
}

extern "C" void kernel_launch(void* const* d_in, const int* in_sizes, int n_in,
                              void* d_out, int out_size, void* d_ws, size_t ws_size,
                              hipStream_t stream) {
  ResParams rp;
  double b = exp((log(2048.0) - log(16.0)) / 23.0);
  for (int l = 0; l < LVL; ++l) rp.r[l] = (float)floor(16.0 * pow(b, (double)l));

  const float* pts  = (const float*)d_in[0];
  const float* dirs = (const float*)d_in[1];
  const float* tbl  = (const float*)d_in[2];
  float* outp = (float*)d_out;

  int n = in_sizes[0] / 3;            // 524288
  int mlp_blocks = n / 64;            // 8192
  size_t enc_bytes = (size_t)LVL * (size_t)n * 4u;
  size_t img_bytes = (size_t)S1_SHORTS * 2 + (size_t)S2_SHORTS * 2 + 272 * 4 + 144 * 4;

  if (ws_size >= enc_bytes + img_bytes) {
    unsigned* enc2 = (unsigned*)d_ws;
    char* base = (char*)d_ws + enc_bytes;
    short* Wimg1 = (short*)base;
    short* Wimg2 = (short*)(base + S1_SHORTS * 2);
    float* Bimg1 = (float*)(base + S1_SHORTS * 2 + S2_SHORTS * 2);
    float* Bimg2 = (float*)(base + S1_SHORTS * 2 + S2_SHORTS * 2 + 272 * 4);

    prep_weights<<<8, 256, 0, stream>>>(
        (const float*)d_in[3],  (const float*)d_in[4],
        (const float*)d_in[5],  (const float*)d_in[6],
        (const float*)d_in[7],  (const float*)d_in[8],
        (const float*)d_in[9],  (const float*)d_in[10],
        (const float*)d_in[11], (const float*)d_in[12],
        (const float*)d_in[13], (const float*)d_in[14],
        (const float*)d_in[15], (const float*)d_in[16],
        Wimg1, Wimg2, Bimg1, Bimg2);

    int enc_blocks = LVL * (n / 256);
    hash_encode_k<<<enc_blocks, 256, 0, stream>>>(pts, tbl, enc2, n, rp);

    mlp_k<true><<<mlp_blocks, 256, 0, stream>>>(
        dirs, enc2,
        (const float*)d_in[3],  (const float*)d_in[4],
        (const float*)d_in[5],  (const float*)d_in[6],
        (const float*)d_in[7],  (const float*)d_in[8],
        (const float*)d_in[9],  (const float*)d_in[10],
        (const float*)d_in[11], (const float*)d_in[12],
        (const float*)d_in[13], (const float*)d_in[14],
        (const float*)d_in[15], (const float*)d_in[16],
        Wimg1, Wimg2, Bimg1, Bimg2,
        outp, n);
  } else if (ws_size >= enc_bytes) {
    unsigned* enc2 = (unsigned*)d_ws;
    int enc_blocks = LVL * (n / 256);
    hash_encode_k<<<enc_blocks, 256, 0, stream>>>(pts, tbl, enc2, n, rp);
    mlp_k<false><<<mlp_blocks, 256, 0, stream>>>(
        dirs, enc2,
        (const float*)d_in[3],  (const float*)d_in[4],
        (const float*)d_in[5],  (const float*)d_in[6],
        (const float*)d_in[7],  (const float*)d_in[8],
        (const float*)d_in[9],  (const float*)d_in[10],
        (const float*)d_in[11], (const float*)d_in[12],
        (const float*)d_in[13], (const float*)d_in[14],
        (const float*)d_in[15], (const float*)d_in[16],
        nullptr, nullptr, nullptr, nullptr,
        outp, n);
  } else {
    nerf_fused<<<mlp_blocks, 256, 0, stream>>>(
        pts, dirs, tbl,
        (const float*)d_in[3],  (const float*)d_in[4],
        (const float*)d_in[5],  (const float*)d_in[6],
        (const float*)d_in[7],  (const float*)d_in[8],
        (const float*)d_in[9],  (const float*)d_in[10],
        (const float*)d_in[11], (const float*)d_in[12],
        (const float*)d_in[13], (const float*)d_in[14],
        (const float*)d_in[15], (const float*)d_in[16],
        outp, n, rp);
  }
}

// Round 5
// 529.209 us; speedup vs baseline: 2.4088x; 1.3173x over previous
//
#include <hip/hip_runtime.h>
#include <math.h>

#define LVL 24
#define TMASK ((1u << 19) - 1u)

typedef short short8 __attribute__((ext_vector_type(8)));
typedef float floatx4 __attribute__((ext_vector_type(4)));

struct ResParams { float r[LVL]; };

__device__ __forceinline__ float bf2f(unsigned short b) {
  union { unsigned u; float f; } t; t.u = ((unsigned)b) << 16; return t.f;
}
__device__ __forceinline__ unsigned short f2bf(float f) {
  union { float f; unsigned u; } t; t.f = f;
  unsigned u = t.u;
  u += 0x7FFFu + ((u >> 16) & 1u);   // RNE
  return (unsigned short)(u >> 16);
}
// Fast exact-form gelu: A&S 7.1.26 erf, |err| < 1.5e-7, branch-free.
__device__ __forceinline__ float geluf(float x) {
  float a = fabsf(x) * 0.7071067811865476f;
  float t = __builtin_amdgcn_rcpf(fmaf(0.3275911f, a, 1.0f));
  float p = fmaf(t, 1.061405429f, -1.453152027f);
  p = fmaf(t, p, 1.421413741f);
  p = fmaf(t, p, -0.284496736f);
  p = fmaf(t, p, 0.254829592f);
  float er = 1.0f - p * t * __expf(-a * a);
  return 0.5f * x * (1.0f + copysignf(er, x));
}
__device__ __forceinline__ floatx4 mfma16(short8 a, short8 b, floatx4 c) {
  return __builtin_amdgcn_mfma_f32_16x16x32_bf16(a, b, c, 0, 0, 0);
}

// Fragment-ordered weight image offsets.
// Short offsets (prep):           short8 offsets (mlp):
#define L0_W 0
#define L1_W 4096
#define L2_W 8192
#define L3_W 12288
#define L4_W 17408
#define L5_W 23552
#define L6_W 27648
#define WIMG_SHORTS 28672
#define L0_F 0
#define L1_F 512
#define L2_F 1024
#define L3_F 1536
#define L4_F 2176
#define L5_F 2944
#define L6_F 3456

// ---------------------------------------------------------------------------
// Prep: fragment-ordered bf16 weight images + bias image.
// frag idx ((c*CBS+cb)*64+lane)*8+j  <->  n=cb*16+(lane&15), k=c*32+(lane>>4)*8+j
// ---------------------------------------------------------------------------
__device__ void prepF(const float* w, short* dst, int K, int NOUT, int KCH, int CBS) {
  int total = KCH * CBS * 64 * 8;
  for (int i = threadIdx.x; i < total; i += 256) {
    int j = i & 7;
    int lane = (i >> 3) & 63;
    int cbc = i >> 9;
    int cb = cbc % CBS;
    int c  = cbc / CBS;
    int n = cb * 16 + (lane & 15);
    int k = c * 32 + (lane >> 4) * 8 + j;
    short v = 0;
    if (k < K && n < NOUT) v = (short)f2bf(w[k * NOUT + n]);
    dst[i] = v;
  }
}
__global__ __launch_bounds__(256) void prep_weights(
    const float* __restrict__ fw0, const float* __restrict__ fb0,
    const float* __restrict__ fw1, const float* __restrict__ fb1,
    const float* __restrict__ fw2, const float* __restrict__ fb2,
    const float* __restrict__ fw3, const float* __restrict__ fb3,
    const float* __restrict__ rw0, const float* __restrict__ rb0,
    const float* __restrict__ rw1, const float* __restrict__ rb1,
    const float* __restrict__ rw2, const float* __restrict__ rb2,
    short* __restrict__ Wimg, float* __restrict__ Bimg)
{
  int b = blockIdx.x, tid = threadIdx.x;
  switch (b) {
    case 0: prepF(fw0, Wimg + L0_W, 48, 64, 2, 4); break;
    case 1: prepF(fw1, Wimg + L1_W, 64, 64, 2, 4); break;
    case 2: prepF(fw2, Wimg + L2_W, 64, 64, 2, 4); break;
    case 3: prepF(fw3, Wimg + L3_W, 64, 65, 2, 5); break;
    case 4: prepF(rw0, Wimg + L4_W, 73, 64, 3, 4); break;
    case 5: prepF(rw1, Wimg + L5_W, 64, 64, 2, 4); break;
    case 6: prepF(rw2, Wimg + L6_W, 64,  3, 2, 1); break;
    case 7:
      if (tid < 64) {
        Bimg[tid]       = fb0[tid];
        Bimg[64 + tid]  = fb1[tid];
        Bimg[128 + tid] = fb2[tid];
        Bimg[272 + tid] = rb0[tid];
        Bimg[336 + tid] = rb1[tid];
      }
      if (tid < 80) Bimg[192 + tid] = (tid < 65) ? fb3[tid] : 0.0f;
      if (tid < 16) Bimg[400 + tid] = (tid < 3) ? rb2[tid] : 0.0f;
      break;
  }
}

// Pack f32 table -> bf16x2 (4B entries).
__global__ __launch_bounds__(256) void tbl_pack(
    const float* __restrict__ t, unsigned* __restrict__ q, int nent)
{
  int g = blockIdx.x * 256 + threadIdx.x;
  int stride = gridDim.x * 256;
  for (int e = g; e < nent; e += stride) {
    float2 v = *(const float2*)(t + (size_t)2 * e);
    q[e] = (unsigned)f2bf(v.x) | ((unsigned)f2bf(v.y) << 16);
  }
}

// ---------------------------------------------------------------------------
// Hash-grid encode. One thread per (level, point), level-major grid.
// x-prime is 1 => when c0 even, x-corner pair hashes to adjacent indices h,h^1
// -> one paired load (25% fewer L2 requests on average).
// ---------------------------------------------------------------------------
template<bool PACKED>
__global__ __launch_bounds__(256) void hash_encode_k(
    const float* __restrict__ pts, const float* __restrict__ tbl,
    const unsigned* __restrict__ tblq, unsigned* __restrict__ enc2,
    int N, ResParams rp)
{
  int bid = blockIdx.x;
  int l   = bid >> 11;                       // 2048 blocks per level
  int p   = ((bid & 2047) << 8) + threadIdx.x;
  float res = rp.r[l];

  float x = (pts[p * 3 + 0] + 1.0f) * 0.5f * res;
  float y = (pts[p * 3 + 1] + 1.0f) * 0.5f * res;
  float z = (pts[p * 3 + 2] + 1.0f) * 0.5f * res;
  float fx = floorf(x), fy = floorf(y), fz = floorf(z);
  float w0 = x - fx, w1 = y - fy, w2 = z - fz;
  unsigned c0 = (unsigned)fx, c1 = (unsigned)fy, c2 = (unsigned)fz;
  unsigned hy0 = c1 * 2654435761u, hy1 = hy0 + 2654435761u;
  unsigned hz0 = c2 * 805459861u,  hz1 = hz0 + 805459861u;
  bool ceven = ((c0 & 1u) == 0u);

  const unsigned* tq = PACKED ? (tblq + ((size_t)l << 19)) : nullptr;
  const float*    tf = PACKED ? nullptr : (tbl + ((size_t)l << 20));

  float f0 = 0.f, f1 = 0.f;
  #pragma unroll
  for (int yz = 0; yz < 4; ++yz) {
    unsigned hyz = ((yz & 2) ? hy1 : hy0) ^ ((yz & 1) ? hz1 : hz0);
    float wyz = ((yz & 2) ? w1 : 1.f - w1) * ((yz & 1) ? w2 : 1.f - w2);
    unsigned h0 = (c0 ^ hyz) & TMASK;          // x-corner c0   (weight 1-w0)
    unsigned h1 = ((c0 + 1u) ^ hyz) & TMASK;   // x-corner c0+1 (weight w0)
    float e00, e01, e10, e11;
    if constexpr (PACKED) {
      unsigned v0, v1;
      if (ceven) {                              // h1 == h0^1
        uint2 v = *(const uint2*)(tq + (h0 & ~1u));
        v0 = (h0 & 1u) ? v.y : v.x;
        v1 = (h0 & 1u) ? v.x : v.y;
      } else {
        v0 = tq[h0];
        v1 = tq[h1];
      }
      e00 = bf2f((unsigned short)(v0 & 0xffffu)); e01 = bf2f((unsigned short)(v0 >> 16));
      e10 = bf2f((unsigned short)(v1 & 0xffffu)); e11 = bf2f((unsigned short)(v1 >> 16));
    } else {
      if (ceven) {
        float4 v = *(const float4*)(tf + 2u * (h0 & ~1u));
        if (h0 & 1u) { e00 = v.z; e01 = v.w; e10 = v.x; e11 = v.y; }
        else         { e00 = v.x; e01 = v.y; e10 = v.z; e11 = v.w; }
      } else {
        float2 a = *(const float2*)(tf + 2u * h0);
        float2 b = *(const float2*)(tf + 2u * h1);
        e00 = a.x; e01 = a.y; e10 = b.x; e11 = b.y;
      }
    }
    float wa = (1.f - w0) * wyz, wb = w0 * wyz;
    f0 += wa * e00 + wb * e10;
    f1 += wa * e01 + wb * e11;
  }
  enc2[l * N + p] = (unsigned)f2bf(f0) | ((unsigned)f2bf(f1) << 16);
}

// ---------------------------------------------------------------------------
// MLP: B-fragments read straight from global weight image (L1-resident,
// 1KB coalesced wave loads). A-tile is wave-private LDS -> one barrier total.
// ---------------------------------------------------------------------------
template<int KCH, int CBS>
__device__ __forceinline__ void run_layer_g(const short* At, const short8* Wf,
                                            int lane, int m, int quad, floatx4* acc) {
  #pragma unroll
  for (int cb = 0; cb < CBS; ++cb) acc[cb] = (floatx4){0.f, 0.f, 0.f, 0.f};
  #pragma unroll
  for (int c = 0; c < KCH; ++c) {
    short8 a = *(const short8*)(At + m * 104 + c * 32 + quad * 8);
    #pragma unroll
    for (int cb = 0; cb < CBS; ++cb) {
      short8 b = Wf[(c * CBS + cb) * 64 + lane];
      acc[cb] = mfma16(a, b, acc[cb]);
    }
  }
}

__global__ __launch_bounds__(256, 4) void mlp_g(
    const float* __restrict__ dirs,
    const unsigned* __restrict__ enc2,
    const short* __restrict__ Wimg, const float* __restrict__ Bimg,
    float* __restrict__ outp, int Nrows)
{
  __shared__ __align__(16) short Atile[4 * 16 * 104];
  __shared__ __align__(16) float Blds[416];

  const int tid  = threadIdx.x;
  const int wave = tid >> 6;
  const int lane = tid & 63;
  const int m    = lane & 15;
  const int quad = lane >> 4;
  const int row0 = blockIdx.x * 64 + wave * 16;
  short* At = Atile + wave * (16 * 104);
  const short8* Wf = (const short8*)Wimg;

  if (tid < 104) ((float4*)Blds)[tid] = ((const float4*)Bimg)[tid];

  // SH3 dirs at k=64..72, zeros k=48..63 / 73..103
  if (lane < 16) {
    int row = row0 + lane;
    float dx = dirs[row * 3 + 0];
    float dy = dirs[row * 3 + 1];
    float dz = dirs[row * 3 + 2];
    short8 z8 = {0, 0, 0, 0, 0, 0, 0, 0};
    short8 s07;
    s07[0] = (short)f2bf(0.28209479177387814f);
    s07[1] = (short)f2bf(-0.48860251190291987f * dy);
    s07[2] = (short)f2bf(0.48860251190291987f * dz);
    s07[3] = (short)f2bf(-0.48860251190291987f * dx);
    s07[4] = (short)f2bf(1.0925484305920792f * dx * dy);
    s07[5] = (short)f2bf(-1.0925484305920792f * dy * dz);
    s07[6] = (short)f2bf(0.31539156525252005f * (3.0f * dz * dz - 1.0f));
    s07[7] = (short)f2bf(-1.0925484305920792f * dx * dz);
    short8 s8v = {0, 0, 0, 0, 0, 0, 0, 0};
    s8v[0] = (short)f2bf(0.5462742152960396f * (dx * dx - dy * dy));
    short* rb = At + lane * 104;
    *(short8*)(rb + 48) = z8;
    *(short8*)(rb + 56) = z8;
    *(short8*)(rb + 64) = s07;
    *(short8*)(rb + 72) = s8v;
    *(short8*)(rb + 80) = z8;
    *(short8*)(rb + 88) = z8;
    *(short8*)(rb + 96) = z8;
  }

  // A-tile k=0..47 from enc2 (wave-private)
  for (int i = lane; i < 16 * LVL; i += 64) {
    int l = i >> 4;
    int r = i & 15;
    unsigned v = enc2[l * Nrows + row0 + r];
    *(unsigned*)(At + r * 104 + 2 * l) = v;
  }

  __syncthreads();   // Blds visibility (Atile is wave-private)

  floatx4 acc[5];

  // L0
  run_layer_g<2, 4>(At, Wf + L0_F, lane, m, quad, acc);
  #pragma unroll
  for (int cb = 0; cb < 4; ++cb) {
    float bc = Blds[0 + cb * 16 + m];
    #pragma unroll
    for (int r = 0; r < 4; ++r) {
      float v = geluf(acc[cb][r] + bc);
      At[(quad * 4 + r) * 104 + cb * 16 + m] = (short)f2bf(v);
    }
  }
  // L1
  run_layer_g<2, 4>(At, Wf + L1_F, lane, m, quad, acc);
  #pragma unroll
  for (int cb = 0; cb < 4; ++cb) {
    float bc = Blds[64 + cb * 16 + m];
    #pragma unroll
    for (int r = 0; r < 4; ++r) {
      float v = geluf(acc[cb][r] + bc);
      At[(quad * 4 + r) * 104 + cb * 16 + m] = (short)f2bf(v);
    }
  }
  // L2
  run_layer_g<2, 4>(At, Wf + L2_F, lane, m, quad, acc);
  #pragma unroll
  for (int cb = 0; cb < 4; ++cb) {
    float bc = Blds[128 + cb * 16 + m];
    #pragma unroll
    for (int r = 0; r < 4; ++r) {
      float v = geluf(acc[cb][r] + bc);
      At[(quad * 4 + r) * 104 + cb * 16 + m] = (short)f2bf(v);
    }
  }
  // L3: col0 -> softplus -> density ; cols 1..64 -> gelu -> k=0..63
  run_layer_g<2, 5>(At, Wf + L3_F, lane, m, quad, acc);
  #pragma unroll
  for (int cb = 0; cb < 5; ++cb) {
    int col = cb * 16 + m;
    float bc = Blds[192 + col];
    #pragma unroll
    for (int r = 0; r < 4; ++r) {
      float v = acc[cb][r] + bc;
      int row = quad * 4 + r;
      if (col == 0) {
        float d = (v > 15.f) ? v : __logf(1.0f + __expf(v));
        outp[3 * Nrows + row0 + row] = d;
      } else if (col <= 64) {
        At[row * 104 + (col - 1)] = (short)f2bf(geluf(v));
      }
    }
  }
  // L4: [feat64 | sh9 | 0pad] (K=96) -> 64, gelu
  run_layer_g<3, 4>(At, Wf + L4_F, lane, m, quad, acc);
  #pragma unroll
  for (int cb = 0; cb < 4; ++cb) {
    float bc = Blds[272 + cb * 16 + m];
    #pragma unroll
    for (int r = 0; r < 4; ++r) {
      float v = geluf(acc[cb][r] + bc);
      At[(quad * 4 + r) * 104 + cb * 16 + m] = (short)f2bf(v);
    }
  }
  // L5
  run_layer_g<2, 4>(At, Wf + L5_F, lane, m, quad, acc);
  #pragma unroll
  for (int cb = 0; cb < 4; ++cb) {
    float bc = Blds[336 + cb * 16 + m];
    #pragma unroll
    for (int r = 0; r < 4; ++r) {
      float v = geluf(acc[cb][r] + bc);
      At[(quad * 4 + r) * 104 + cb * 16 + m] = (short)f2bf(v);
    }
  }
  // L6: 64 -> 3, sigmoid -> rgb
  run_layer_g<2, 1>(At, Wf + L6_F, lane, m, quad, acc);
  {
    float bc = Blds[400 + m];
    #pragma unroll
    for (int r = 0; r < 4; ++r) {
      float v = acc[0][r] + bc;
      float s = __builtin_amdgcn_rcpf(1.0f + __expf(-v));
      if (m < 3) outp[(row0 + quad * 4 + r) * 3 + m] = s;
    }
  }
}

// ---------------------------------------------------------------------------
// Fallback: fully fused kernel (used only if ws too small).
// ---------------------------------------------------------------------------
#define W0_OFF 0
#define W1_OFF 4608
#define W2_OFF 9216
#define W3_OFF 13824
#define R0_OFF 0
#define R1_OFF 6656
#define R2_OFF 11264

template<int K, int NOUT, int NROWS, int STRIDE>
__device__ void stageW(const float* w, short* dst, int tid) {
  for (int i = tid; i < NROWS * STRIDE; i += 256) {
    int n = i / STRIDE;
    int k = i - n * STRIDE;
    short v = 0;
    if (n < NOUT && k < K) v = (short)f2bf(w[k * NOUT + n]);
    dst[i] = v;
  }
}
template<int NOUT, int NPAD>
__device__ void stageB(const float* b, float* dst, int tid) {
  for (int i = tid; i < NPAD; i += 256) dst[i] = (i < NOUT) ? b[i] : 0.0f;
}
template<int KCH, int CBS, int WSTRIDE>
__device__ __forceinline__ void run_layer(const short* At, const short* Wb,
                                          int m, int quad, floatx4* acc) {
  #pragma unroll
  for (int cb = 0; cb < CBS; ++cb) acc[cb] = (floatx4){0.f, 0.f, 0.f, 0.f};
  #pragma unroll
  for (int c = 0; c < KCH; ++c) {
    short8 a = *(const short8*)(At + m * 104 + c * 32 + quad * 8);
    #pragma unroll
    for (int cb = 0; cb < CBS; ++cb) {
      short8 b = *(const short8*)(Wb + (cb * 16 + m) * WSTRIDE + c * 32 + quad * 8);
      acc[cb] = mfma16(a, b, acc[cb]);
    }
  }
}

__global__ __launch_bounds__(256, 2) void nerf_fused(
    const float* __restrict__ pts,
    const float* __restrict__ dirs,
    const float* __restrict__ tbl,
    const float* __restrict__ fw0, const float* __restrict__ fb0,
    const float* __restrict__ fw1, const float* __restrict__ fb1,
    const float* __restrict__ fw2, const float* __restrict__ fb2,
    const float* __restrict__ fw3, const float* __restrict__ fb3,
    const float* __restrict__ rw0, const float* __restrict__ rb0,
    const float* __restrict__ rw1, const float* __restrict__ rb1,
    const float* __restrict__ rw2, const float* __restrict__ rb2,
    float* __restrict__ outp, int Nrows, ResParams rp)
{
  __shared__ __align__(16) short Wlds[19584];
  __shared__ __align__(16) float Blds[272];
  __shared__ __align__(16) short Atile[4 * 16 * 104];

  const int tid  = threadIdx.x;
  const int wave = tid >> 6;
  const int lane = tid & 63;
  const int m    = lane & 15;
  const int quad = lane >> 4;
  const int row0 = blockIdx.x * 64 + wave * 16;
  short* At = Atile + wave * (16 * 104);

  stageW<48, 64, 64, 72>(fw0, Wlds + W0_OFF, tid);
  stageW<64, 64, 64, 72>(fw1, Wlds + W1_OFF, tid);
  stageW<64, 64, 64, 72>(fw2, Wlds + W2_OFF, tid);
  stageW<64, 65, 80, 72>(fw3, Wlds + W3_OFF, tid);
  stageB<64, 64>(fb0, Blds + 0,   tid);
  stageB<64, 64>(fb1, Blds + 64,  tid);
  stageB<64, 64>(fb2, Blds + 128, tid);
  stageB<65, 80>(fb3, Blds + 192, tid);

  if (lane < 16) {
    int row = row0 + lane;
    float dx = dirs[row * 3 + 0];
    float dy = dirs[row * 3 + 1];
    float dz = dirs[row * 3 + 2];
    short8 z8 = {0, 0, 0, 0, 0, 0, 0, 0};
    short8 s07;
    s07[0] = (short)f2bf(0.28209479177387814f);
    s07[1] = (short)f2bf(-0.48860251190291987f * dy);
    s07[2] = (short)f2bf(0.48860251190291987f * dz);
    s07[3] = (short)f2bf(-0.48860251190291987f * dx);
    s07[4] = (short)f2bf(1.0925484305920792f * dx * dy);
    s07[5] = (short)f2bf(-1.0925484305920792f * dy * dz);
    s07[6] = (short)f2bf(0.31539156525252005f * (3.0f * dz * dz - 1.0f));
    s07[7] = (short)f2bf(-1.0925484305920792f * dx * dz);
    short8 s8v = {0, 0, 0, 0, 0, 0, 0, 0};
    s8v[0] = (short)f2bf(0.5462742152960396f * (dx * dx - dy * dy));
    short* rb = At + lane * 104;
    *(short8*)(rb + 48) = z8;
    *(short8*)(rb + 56) = z8;
    *(short8*)(rb + 64) = s07;
    *(short8*)(rb + 72) = s8v;
    *(short8*)(rb + 80) = z8;
    *(short8*)(rb + 88) = z8;
    *(short8*)(rb + 96) = z8;
  }

  for (int t = lane; t < 16 * LVL; t += 64) {
    int r = t / LVL;
    int l = t - r * LVL;
    int row = row0 + r;
    float res = rp.r[l];
    float x = (pts[row * 3 + 0] + 1.0f) * 0.5f * res;
    float y = (pts[row * 3 + 1] + 1.0f) * 0.5f * res;
    float z = (pts[row * 3 + 2] + 1.0f) * 0.5f * res;
    float fx = floorf(x), fy = floorf(y), fz = floorf(z);
    float w0 = x - fx, w1 = y - fy, w2 = z - fz;
    unsigned c0 = (unsigned)fx, c1 = (unsigned)fy, c2 = (unsigned)fz;
    unsigned ha0 = c0, hb0 = c0 + 1u;
    unsigned ha1 = c1 * 2654435761u, hb1 = ha1 + 2654435761u;
    unsigned ha2 = c2 * 805459861u,  hb2 = ha2 + 805459861u;
    const float* tb = tbl + ((size_t)l << 20);
    float f0 = 0.f, f1 = 0.f;
    #pragma unroll
    for (int i = 0; i < 8; ++i) {
      unsigned h = ((i & 4) ? hb0 : ha0) ^ ((i & 2) ? hb1 : ha1) ^ ((i & 1) ? hb2 : ha2);
      float wt = ((i & 4) ? w0 : 1.f - w0) * ((i & 2) ? w1 : 1.f - w1) * ((i & 1) ? w2 : 1.f - w2);
      float2 fv = *(const float2*)(tb + 2u * (h & TMASK));
      f0 += wt * fv.x;
      f1 += wt * fv.y;
    }
    unsigned pk = (unsigned)f2bf(f0) | ((unsigned)f2bf(f1) << 16);
    *(unsigned*)(At + r * 104 + 2 * l) = pk;
  }

  __syncthreads();

  floatx4 acc[5];

  run_layer<2, 4, 72>(At, Wlds + W0_OFF, m, quad, acc);
  #pragma unroll
  for (int cb = 0; cb < 4; ++cb) {
    float bc = Blds[0 + cb * 16 + m];
    #pragma unroll
    for (int r = 0; r < 4; ++r) {
      float v = geluf(acc[cb][r] + bc);
      At[(quad * 4 + r) * 104 + cb * 16 + m] = (short)f2bf(v);
    }
  }
  run_layer<2, 4, 72>(At, Wlds + W1_OFF, m, quad, acc);
  #pragma unroll
  for (int cb = 0; cb < 4; ++cb) {
    float bc = Blds[64 + cb * 16 + m];
    #pragma unroll
    for (int r = 0; r < 4; ++r) {
      float v = geluf(acc[cb][r] + bc);
      At[(quad * 4 + r) * 104 + cb * 16 + m] = (short)f2bf(v);
    }
  }
  run_layer<2, 4, 72>(At, Wlds + W2_OFF, m, quad, acc);
  #pragma unroll
  for (int cb = 0; cb < 4; ++cb) {
    float bc = Blds[128 + cb * 16 + m];
    #pragma unroll
    for (int r = 0; r < 4; ++r) {
      float v = geluf(acc[cb][r] + bc);
      At[(quad * 4 + r) * 104 + cb * 16 + m] = (short)f2bf(v);
    }
  }
  run_layer<2, 5, 72>(At, Wlds + W3_OFF, m, quad, acc);
  #pragma unroll
  for (int cb = 0; cb < 5; ++cb) {
    int col = cb * 16 + m;
    float bc = Blds[192 + col];
    #pragma unroll
    for (int r = 0; r < 4; ++r) {
      float v = acc[cb][r] + bc;
      int row = quad * 4 + r;
      if (col == 0) {
        float d = (v > 15.f) ? v : __logf(1.0f + __expf(v));
        outp[3 * Nrows + row0 + row] = d;
      } else if (col <= 64) {
        At[row * 104 + (col - 1)] = (short)f2bf(geluf(v));
      }
    }
  }

  __syncthreads();

  stageW<73, 64, 64, 104>(rw0, Wlds + R0_OFF, tid);
  stageW<64, 64, 64,  72>(rw1, Wlds + R1_OFF, tid);
  stageW<64,  3, 16,  72>(rw2, Wlds + R2_OFF, tid);
  stageB<64, 64>(rb0, Blds + 0,   tid);
  stageB<64, 64>(rb1, Blds + 64,  tid);
  stageB< 3, 16>(rb2, Blds + 128, tid);

  __syncthreads();

  run_layer<3, 4, 104>(At, Wlds + R0_OFF, m, quad, acc);
  #pragma unroll
  for (int cb = 0; cb < 4; ++cb) {
    float bc = Blds[0 + cb * 16 + m];
    #pragma unroll
    for (int r = 0; r < 4; ++r) {
      float v = geluf(acc[cb][r] + bc);
      At[(quad * 4 + r) * 104 + cb * 16 + m] = (short)f2bf(v);
    }
  }
  run_layer<2, 4, 72>(At, Wlds + R1_OFF, m, quad, acc);
  #pragma unroll
  for (int cb = 0; cb < 4; ++cb) {
    float bc = Blds[64 + cb * 16 + m];
    #pragma unroll
    for (int r = 0; r < 4; ++r) {
      float v = geluf(acc[cb][r] + bc);
      At[(quad * 4 + r) * 104 + cb * 16 + m] = (short)f2bf(v);
    }
  }
  run_layer<2, 1, 72>(At, Wlds + R2_OFF, m, quad, acc);
  {
    float bc = Blds[128 + m];
    #pragma unroll
    for (int r = 0; r < 4; ++r) {
      float v = acc[0][r] + bc;
      float s = __builtin_amdgcn_rcpf(1.0f + __expf(-v));
      if (m < 3) outp[(row0 + quad * 4 + r) * 3 + m] = s;
    }
  }
}

extern "C" void kernel_launch(void* const* d_in, const int* in_sizes, int n_in,
                              void* d_out, int out_size, void* d_ws, size_t ws_size,
                              hipStream_t stream) {
  ResParams rp;
  double b = exp((log(2048.0) - log(16.0)) / 23.0);
  for (int l = 0; l < LVL; ++l) rp.r[l] = (float)floor(16.0 * pow(b, (double)l));

  const float* pts  = (const float*)d_in[0];
  const float* dirs = (const float*)d_in[1];
  const float* tbl  = (const float*)d_in[2];
  float* outp = (float*)d_out;

  int n = in_sizes[0] / 3;                 // 524288
  int mlp_blocks = n / 64;                 // 8192
  int nent = LVL << 19;                    // 12.58M table entries
  size_t enc_b = (size_t)LVL * (size_t)n * 4u;        // 50.3 MB
  size_t img_reserve = 65536;                          // Wimg(57344B)+Bimg(1664B)
  size_t tbl_b = (size_t)nent * 4u;                    // 50.3 MB
  size_t full_need = enc_b + img_reserve + tbl_b;
  size_t mid_need  = enc_b + img_reserve;

  unsigned* enc2 = (unsigned*)d_ws;
  short* Wimg = (short*)((char*)d_ws + enc_b);
  float* Bimg = (float*)((char*)d_ws + enc_b + 57344);
  unsigned* tblq = (unsigned*)((char*)d_ws + enc_b + img_reserve);
  int enc_blocks = LVL * (n / 256);

  if (ws_size >= full_need) {
    prep_weights<<<8, 256, 0, stream>>>(
        (const float*)d_in[3],  (const float*)d_in[4],
        (const float*)d_in[5],  (const float*)d_in[6],
        (const float*)d_in[7],  (const float*)d_in[8],
        (const float*)d_in[9],  (const float*)d_in[10],
        (const float*)d_in[11], (const float*)d_in[12],
        (const float*)d_in[13], (const float*)d_in[14],
        (const float*)d_in[15], (const float*)d_in[16],
        Wimg, Bimg);
    tbl_pack<<<12288, 256, 0, stream>>>(tbl, tblq, nent);
    hash_encode_k<true><<<enc_blocks, 256, 0, stream>>>(pts, tbl, tblq, enc2, n, rp);
    mlp_g<<<mlp_blocks, 256, 0, stream>>>(dirs, enc2, Wimg, Bimg, outp, n);
  } else if (ws_size >= mid_need) {
    prep_weights<<<8, 256, 0, stream>>>(
        (const float*)d_in[3],  (const float*)d_in[4],
        (const float*)d_in[5],  (const float*)d_in[6],
        (const float*)d_in[7],  (const float*)d_in[8],
        (const float*)d_in[9],  (const float*)d_in[10],
        (const float*)d_in[11], (const float*)d_in[12],
        (const float*)d_in[13], (const float*)d_in[14],
        (const float*)d_in[15], (const float*)d_in[16],
        Wimg, Bimg);
    hash_encode_k<false><<<enc_blocks, 256, 0, stream>>>(pts, tbl, nullptr, enc2, n, rp);
    mlp_g<<<mlp_blocks, 256, 0, stream>>>(dirs, enc2, Wimg, Bimg, outp, n);
  } else {
    nerf_fused<<<mlp_blocks, 256, 0, stream>>>(
        pts, dirs, tbl,
        (const float*)d_in[3],  (const float*)d_in[4],
        (const float*)d_in[5],  (const float*)d_in[6],
        (const float*)d_in[7],  (const float*)d_in[8],
        (const float*)d_in[9],  (const float*)d_in[10],
        (const float*)d_in[11], (const float*)d_in[12],
        (const float*)d_in[13], (const float*)d_in[14],
        (const float*)d_in[15], (const float*)d_in[16],
        outp, n, rp);
  }
}

// Round 6
// 526.768 us; speedup vs baseline: 2.4200x; 1.0046x over previous
//
#include <hip/hip_runtime.h>
#include <math.h>

#define LVL 24
#define TMASK ((1u << 19) - 1u)

typedef short short8 __attribute__((ext_vector_type(8)));
typedef float floatx4 __attribute__((ext_vector_type(4)));

struct ResParams { float r[LVL]; };

__device__ __forceinline__ float bf2f(unsigned short b) {
  union { unsigned u; float f; } t; t.u = ((unsigned)b) << 16; return t.f;
}
__device__ __forceinline__ unsigned short f2bf(float f) {
  union { float f; unsigned u; } t; t.f = f;
  unsigned u = t.u;
  u += 0x7FFFu + ((u >> 16) & 1u);   // RNE
  return (unsigned short)(u >> 16);
}
// Fast exact-form gelu: A&S 7.1.26 erf, |err| < 1.5e-7, branch-free.
__device__ __forceinline__ float geluf(float x) {
  float a = fabsf(x) * 0.7071067811865476f;
  float t = __builtin_amdgcn_rcpf(fmaf(0.3275911f, a, 1.0f));
  float p = fmaf(t, 1.061405429f, -1.453152027f);
  p = fmaf(t, p, 1.421413741f);
  p = fmaf(t, p, -0.284496736f);
  p = fmaf(t, p, 0.254829592f);
  float er = 1.0f - p * t * __expf(-a * a);
  return 0.5f * x * (1.0f + copysignf(er, x));
}
__device__ __forceinline__ floatx4 mfma16(short8 a, short8 b, floatx4 c) {
  return __builtin_amdgcn_mfma_f32_16x16x32_bf16(a, b, c, 0, 0, 0);
}

// Fragment-ordered weight image offsets (shorts / short8).
#define L0_W 0
#define L1_W 4096
#define L2_W 8192
#define L3_W 12288
#define L4_W 17408
#define L5_W 23552
#define L6_W 27648
#define WIMG_SHORTS 28672
#define L0_F 0
#define L1_F 512
#define L2_F 1024
#define L3_F 1536
#define L4_F 2176
#define L5_F 2944
#define L6_F 3456

// ---------------------------------------------------------------------------
// Prep (fused): blocks 0-7 build fragment-ordered bf16 weight images + bias
// image; blocks 8+ pack the f32 table to bf16x2.
// frag idx ((c*CBS+cb)*64+lane)*8+j <-> n=cb*16+(lane&15), k=c*32+(lane>>4)*8+j
// ---------------------------------------------------------------------------
__device__ void prepF(const float* w, short* dst, int K, int NOUT, int KCH, int CBS) {
  int total = KCH * CBS * 64 * 8;
  for (int i = threadIdx.x; i < total; i += 256) {
    int j = i & 7;
    int lane = (i >> 3) & 63;
    int cbc = i >> 9;
    int cb = cbc % CBS;
    int c  = cbc / CBS;
    int n = cb * 16 + (lane & 15);
    int k = c * 32 + (lane >> 4) * 8 + j;
    short v = 0;
    if (k < K && n < NOUT) v = (short)f2bf(w[k * NOUT + n]);
    dst[i] = v;
  }
}
__global__ __launch_bounds__(256) void prep_all(
    const float* __restrict__ fw0, const float* __restrict__ fb0,
    const float* __restrict__ fw1, const float* __restrict__ fb1,
    const float* __restrict__ fw2, const float* __restrict__ fb2,
    const float* __restrict__ fw3, const float* __restrict__ fb3,
    const float* __restrict__ rw0, const float* __restrict__ rb0,
    const float* __restrict__ rw1, const float* __restrict__ rb1,
    const float* __restrict__ rw2, const float* __restrict__ rb2,
    short* __restrict__ Wimg, float* __restrict__ Bimg,
    const float* __restrict__ tbl, unsigned* __restrict__ tblq, int nent,
    int pack_on)
{
  int b = blockIdx.x, tid = threadIdx.x;
  if (b >= 8) {
    if (!pack_on) return;
    int g = (b - 8) * 256 + tid;
    int stride = (gridDim.x - 8) * 256;
    for (int e = g; e < nent; e += stride) {
      float2 v = *(const float2*)(tbl + (size_t)2 * e);
      tblq[e] = (unsigned)f2bf(v.x) | ((unsigned)f2bf(v.y) << 16);
    }
    return;
  }
  switch (b) {
    case 0: prepF(fw0, Wimg + L0_W, 48, 64, 2, 4); break;
    case 1: prepF(fw1, Wimg + L1_W, 64, 64, 2, 4); break;
    case 2: prepF(fw2, Wimg + L2_W, 64, 64, 2, 4); break;
    case 3: prepF(fw3, Wimg + L3_W, 64, 65, 2, 5); break;
    case 4: prepF(rw0, Wimg + L4_W, 73, 64, 3, 4); break;
    case 5: prepF(rw1, Wimg + L5_W, 64, 64, 2, 4); break;
    case 6: prepF(rw2, Wimg + L6_W, 64,  3, 2, 1); break;
    case 7:
      if (tid < 64) {
        Bimg[tid]       = fb0[tid];
        Bimg[64 + tid]  = fb1[tid];
        Bimg[128 + tid] = fb2[tid];
        Bimg[272 + tid] = rb0[tid];
        Bimg[336 + tid] = rb1[tid];
      }
      if (tid < 80) Bimg[192 + tid] = (tid < 65) ? fb3[tid] : 0.0f;
      if (tid < 16) Bimg[400 + tid] = (tid < 3) ? rb2[tid] : 0.0f;
      break;
  }
}

// ---------------------------------------------------------------------------
// Hash-grid encode. One thread per (level, point), level-major grid.
// pts staged cooperatively through wave-private LDS (3 coalesced 256B
// wave-loads instead of 3 stride-12B scalar loads).
// x-prime == 1 => even-c0 x-corner pairs are one paired load.
// ---------------------------------------------------------------------------
template<bool PACKED>
__global__ __launch_bounds__(256) void hash_encode_k(
    const float* __restrict__ pts, const float* __restrict__ tbl,
    const unsigned* __restrict__ tblq, unsigned* __restrict__ enc2,
    int N, ResParams rp)
{
  __shared__ float pbuf[4][192];
  int bid  = blockIdx.x;
  int wave = threadIdx.x >> 6;
  int lane = threadIdx.x & 63;
  int l    = bid >> 11;                       // 2048 blocks per level
  int p0   = ((bid & 2047) << 8) + wave * 64;
  int p    = p0 + lane;
  float res = rp.r[l];

  {
    const float* pf = pts + (size_t)p0 * 3;
    pbuf[wave][lane]       = pf[lane];
    pbuf[wave][64 + lane]  = pf[64 + lane];
    pbuf[wave][128 + lane] = pf[128 + lane];
  }
  // wave-private region: compiler's lgkmcnt wait orders write->read
  float x = (pbuf[wave][lane * 3 + 0] + 1.0f) * 0.5f * res;
  float y = (pbuf[wave][lane * 3 + 1] + 1.0f) * 0.5f * res;
  float z = (pbuf[wave][lane * 3 + 2] + 1.0f) * 0.5f * res;

  float fx = floorf(x), fy = floorf(y), fz = floorf(z);
  float w0 = x - fx, w1 = y - fy, w2 = z - fz;
  unsigned c0 = (unsigned)fx, c1 = (unsigned)fy, c2 = (unsigned)fz;
  unsigned hy0 = c1 * 2654435761u, hy1 = hy0 + 2654435761u;
  unsigned hz0 = c2 * 805459861u,  hz1 = hz0 + 805459861u;
  bool ceven = ((c0 & 1u) == 0u);

  const unsigned* tq = PACKED ? (tblq + ((size_t)l << 19)) : nullptr;
  const float*    tf = PACKED ? nullptr : (tbl + ((size_t)l << 20));

  float f0 = 0.f, f1 = 0.f;
  #pragma unroll
  for (int yz = 0; yz < 4; ++yz) {
    unsigned hyz = ((yz & 2) ? hy1 : hy0) ^ ((yz & 1) ? hz1 : hz0);
    float wyz = ((yz & 2) ? w1 : 1.f - w1) * ((yz & 1) ? w2 : 1.f - w2);
    unsigned h0 = (c0 ^ hyz) & TMASK;
    unsigned h1 = ((c0 + 1u) ^ hyz) & TMASK;
    float e00, e01, e10, e11;
    if constexpr (PACKED) {
      unsigned v0, v1;
      if (ceven) {                              // h1 == h0^1
        uint2 v = *(const uint2*)(tq + (h0 & ~1u));
        v0 = (h0 & 1u) ? v.y : v.x;
        v1 = (h0 & 1u) ? v.x : v.y;
      } else {
        v0 = tq[h0];
        v1 = tq[h1];
      }
      e00 = bf2f((unsigned short)(v0 & 0xffffu)); e01 = bf2f((unsigned short)(v0 >> 16));
      e10 = bf2f((unsigned short)(v1 & 0xffffu)); e11 = bf2f((unsigned short)(v1 >> 16));
    } else {
      if (ceven) {
        float4 v = *(const float4*)(tf + 2u * (h0 & ~1u));
        if (h0 & 1u) { e00 = v.z; e01 = v.w; e10 = v.x; e11 = v.y; }
        else         { e00 = v.x; e01 = v.y; e10 = v.z; e11 = v.w; }
      } else {
        float2 a = *(const float2*)(tf + 2u * h0);
        float2 b = *(const float2*)(tf + 2u * h1);
        e00 = a.x; e01 = a.y; e10 = b.x; e11 = b.y;
      }
    }
    float wa = (1.f - w0) * wyz, wb = w0 * wyz;
    f0 += wa * e00 + wb * e10;
    f1 += wa * e01 + wb * e11;
  }
  enc2[l * N + p] = (unsigned)f2bf(f0) | ((unsigned)f2bf(f1) << 16);
}

// ---------------------------------------------------------------------------
// MLP: 32 rows per wave (two 16-row tiles share every B-fragment load).
// B-fragments straight from global weight image; A-tiles wave-private LDS.
// ---------------------------------------------------------------------------
template<int KCH, int CBS>
__device__ __forceinline__ void run_layer32(const short* At, const short8* Wf,
                                            int lane, int m, int quad,
                                            floatx4* acc0, floatx4* acc1) {
  #pragma unroll
  for (int cb = 0; cb < CBS; ++cb) {
    acc0[cb] = (floatx4){0.f, 0.f, 0.f, 0.f};
    acc1[cb] = (floatx4){0.f, 0.f, 0.f, 0.f};
  }
  #pragma unroll
  for (int c = 0; c < KCH; ++c) {
    short8 a0 = *(const short8*)(At + m * 104 + c * 32 + quad * 8);
    short8 a1 = *(const short8*)(At + (16 + m) * 104 + c * 32 + quad * 8);
    #pragma unroll
    for (int cb = 0; cb < CBS; ++cb) {
      short8 b = Wf[(c * CBS + cb) * 64 + lane];
      acc0[cb] = mfma16(a0, b, acc0[cb]);
      acc1[cb] = mfma16(a1, b, acc1[cb]);
    }
  }
}

__global__ __launch_bounds__(256, 4) void mlp_g(
    const float* __restrict__ dirs,
    const unsigned* __restrict__ enc2,
    const short* __restrict__ Wimg, const float* __restrict__ Bimg,
    float* __restrict__ outp, int Nrows)
{
  __shared__ __align__(16) short Atile[4 * 32 * 104];
  __shared__ __align__(16) float Blds[416];

  const int tid  = threadIdx.x;
  const int wave = tid >> 6;
  const int lane = tid & 63;
  const int m    = lane & 15;
  const int quad = lane >> 4;
  const int row0 = blockIdx.x * 128 + wave * 32;
  short* At = Atile + wave * (32 * 104);
  const short8* Wf = (const short8*)Wimg;

  if (tid < 104) ((float4*)Blds)[tid] = ((const float4*)Bimg)[tid];

  // SH3 dirs at k=64..72, zeros k=48..63 / 73..103 (32 rows: lanes 0..31)
  if (lane < 32) {
    int row = row0 + lane;
    float dx = dirs[row * 3 + 0];
    float dy = dirs[row * 3 + 1];
    float dz = dirs[row * 3 + 2];
    short8 z8 = {0, 0, 0, 0, 0, 0, 0, 0};
    short8 s07;
    s07[0] = (short)f2bf(0.28209479177387814f);
    s07[1] = (short)f2bf(-0.48860251190291987f * dy);
    s07[2] = (short)f2bf(0.48860251190291987f * dz);
    s07[3] = (short)f2bf(-0.48860251190291987f * dx);
    s07[4] = (short)f2bf(1.0925484305920792f * dx * dy);
    s07[5] = (short)f2bf(-1.0925484305920792f * dy * dz);
    s07[6] = (short)f2bf(0.31539156525252005f * (3.0f * dz * dz - 1.0f));
    s07[7] = (short)f2bf(-1.0925484305920792f * dx * dz);
    short8 s8v = {0, 0, 0, 0, 0, 0, 0, 0};
    s8v[0] = (short)f2bf(0.5462742152960396f * (dx * dx - dy * dy));
    short* rb = At + lane * 104;
    *(short8*)(rb + 48) = z8;
    *(short8*)(rb + 56) = z8;
    *(short8*)(rb + 64) = s07;
    *(short8*)(rb + 72) = s8v;
    *(short8*)(rb + 80) = z8;
    *(short8*)(rb + 88) = z8;
    *(short8*)(rb + 96) = z8;
  }

  // A-tile k=0..47 from enc2 (wave-private): 32 rows x 24 levels
  for (int i = lane; i < 32 * LVL; i += 64) {
    int l = i >> 5;
    int r = i & 31;
    unsigned v = enc2[l * Nrows + row0 + r];
    *(unsigned*)(At + r * 104 + 2 * l) = v;
  }

  __syncthreads();   // Blds visibility (Atile is wave-private)

  floatx4 acc0[5], acc1[5];

  // L0
  run_layer32<2, 4>(At, Wf + L0_F, lane, m, quad, acc0, acc1);
  #pragma unroll
  for (int cb = 0; cb < 4; ++cb) {
    float bc = Blds[0 + cb * 16 + m];
    #pragma unroll
    for (int r = 0; r < 4; ++r) {
      At[(quad * 4 + r) * 104 + cb * 16 + m]      = (short)f2bf(geluf(acc0[cb][r] + bc));
      At[(16 + quad * 4 + r) * 104 + cb * 16 + m] = (short)f2bf(geluf(acc1[cb][r] + bc));
    }
  }
  // L1
  run_layer32<2, 4>(At, Wf + L1_F, lane, m, quad, acc0, acc1);
  #pragma unroll
  for (int cb = 0; cb < 4; ++cb) {
    float bc = Blds[64 + cb * 16 + m];
    #pragma unroll
    for (int r = 0; r < 4; ++r) {
      At[(quad * 4 + r) * 104 + cb * 16 + m]      = (short)f2bf(geluf(acc0[cb][r] + bc));
      At[(16 + quad * 4 + r) * 104 + cb * 16 + m] = (short)f2bf(geluf(acc1[cb][r] + bc));
    }
  }
  // L2
  run_layer32<2, 4>(At, Wf + L2_F, lane, m, quad, acc0, acc1);
  #pragma unroll
  for (int cb = 0; cb < 4; ++cb) {
    float bc = Blds[128 + cb * 16 + m];
    #pragma unroll
    for (int r = 0; r < 4; ++r) {
      At[(quad * 4 + r) * 104 + cb * 16 + m]      = (short)f2bf(geluf(acc0[cb][r] + bc));
      At[(16 + quad * 4 + r) * 104 + cb * 16 + m] = (short)f2bf(geluf(acc1[cb][r] + bc));
    }
  }
  // L3: col0 -> softplus -> density ; cols 1..64 -> gelu -> k=0..63
  run_layer32<2, 5>(At, Wf + L3_F, lane, m, quad, acc0, acc1);
  #pragma unroll
  for (int cb = 0; cb < 5; ++cb) {
    int col = cb * 16 + m;
    float bc = Blds[192 + col];
    #pragma unroll
    for (int r = 0; r < 4; ++r) {
      #pragma unroll
      for (int t = 0; t < 2; ++t) {
        float v = (t ? acc1[cb][r] : acc0[cb][r]) + bc;
        int row = t * 16 + quad * 4 + r;
        if (col == 0) {
          float d = (v > 15.f) ? v : __logf(1.0f + __expf(v));
          outp[3 * Nrows + row0 + row] = d;
        } else if (col <= 64) {
          At[row * 104 + (col - 1)] = (short)f2bf(geluf(v));
        }
      }
    }
  }
  // L4: [feat64 | sh9 | 0pad] (K=96) -> 64, gelu
  run_layer32<3, 4>(At, Wf + L4_F, lane, m, quad, acc0, acc1);
  #pragma unroll
  for (int cb = 0; cb < 4; ++cb) {
    float bc = Blds[272 + cb * 16 + m];
    #pragma unroll
    for (int r = 0; r < 4; ++r) {
      At[(quad * 4 + r) * 104 + cb * 16 + m]      = (short)f2bf(geluf(acc0[cb][r] + bc));
      At[(16 + quad * 4 + r) * 104 + cb * 16 + m] = (short)f2bf(geluf(acc1[cb][r] + bc));
    }
  }
  // L5
  run_layer32<2, 4>(At, Wf + L5_F, lane, m, quad, acc0, acc1);
  #pragma unroll
  for (int cb = 0; cb < 4; ++cb) {
    float bc = Blds[336 + cb * 16 + m];
    #pragma unroll
    for (int r = 0; r < 4; ++r) {
      At[(quad * 4 + r) * 104 + cb * 16 + m]      = (short)f2bf(geluf(acc0[cb][r] + bc));
      At[(16 + quad * 4 + r) * 104 + cb * 16 + m] = (short)f2bf(geluf(acc1[cb][r] + bc));
    }
  }
  // L6: 64 -> 3, sigmoid -> rgb
  run_layer32<2, 1>(At, Wf + L6_F, lane, m, quad, acc0, acc1);
  {
    float bc = Blds[400 + m];
    #pragma unroll
    for (int r = 0; r < 4; ++r) {
      #pragma unroll
      for (int t = 0; t < 2; ++t) {
        float v = (t ? acc1[0][r] : acc0[0][r]) + bc;
        float s = __builtin_amdgcn_rcpf(1.0f + __expf(-v));
        int row = t * 16 + quad * 4 + r;
        if (m < 3) outp[(row0 + row) * 3 + m] = s;
      }
    }
  }
}

// ---------------------------------------------------------------------------
// Fallback: fully fused kernel (used only if ws too small).
// ---------------------------------------------------------------------------
#define W0_OFF 0
#define W1_OFF 4608
#define W2_OFF 9216
#define W3_OFF 13824
#define R0_OFF 0
#define R1_OFF 6656
#define R2_OFF 11264

template<int K, int NOUT, int NROWS, int STRIDE>
__device__ void stageW(const float* w, short* dst, int tid) {
  for (int i = tid; i < NROWS * STRIDE; i += 256) {
    int n = i / STRIDE;
    int k = i - n * STRIDE;
    short v = 0;
    if (n < NOUT && k < K) v = (short)f2bf(w[k * NOUT + n]);
    dst[i] = v;
  }
}
template<int NOUT, int NPAD>
__device__ void stageB(const float* b, float* dst, int tid) {
  for (int i = tid; i < NPAD; i += 256) dst[i] = (i < NOUT) ? b[i] : 0.0f;
}
template<int KCH, int CBS, int WSTRIDE>
__device__ __forceinline__ void run_layer(const short* At, const short* Wb,
                                          int m, int quad, floatx4* acc) {
  #pragma unroll
  for (int cb = 0; cb < CBS; ++cb) acc[cb] = (floatx4){0.f, 0.f, 0.f, 0.f};
  #pragma unroll
  for (int c = 0; c < KCH; ++c) {
    short8 a = *(const short8*)(At + m * 104 + c * 32 + quad * 8);
    #pragma unroll
    for (int cb = 0; cb < CBS; ++cb) {
      short8 b = *(const short8*)(Wb + (cb * 16 + m) * WSTRIDE + c * 32 + quad * 8);
      acc[cb] = mfma16(a, b, acc[cb]);
    }
  }
}

__global__ __launch_bounds__(256, 2) void nerf_fused(
    const float* __restrict__ pts,
    const float* __restrict__ dirs,
    const float* __restrict__ tbl,
    const float* __restrict__ fw0, const float* __restrict__ fb0,
    const float* __restrict__ fw1, const float* __restrict__ fb1,
    const float* __restrict__ fw2, const float* __restrict__ fb2,
    const float* __restrict__ fw3, const float* __restrict__ fb3,
    const float* __restrict__ rw0, const float* __restrict__ rb0,
    const float* __restrict__ rw1, const float* __restrict__ rb1,
    const float* __restrict__ rw2, const float* __restrict__ rb2,
    float* __restrict__ outp, int Nrows, ResParams rp)
{
  __shared__ __align__(16) short Wlds[19584];
  __shared__ __align__(16) float Blds[272];
  __shared__ __align__(16) short Atile[4 * 16 * 104];

  const int tid  = threadIdx.x;
  const int wave = tid >> 6;
  const int lane = tid & 63;
  const int m    = lane & 15;
  const int quad = lane >> 4;
  const int row0 = blockIdx.x * 64 + wave * 16;
  short* At = Atile + wave * (16 * 104);

  stageW<48, 64, 64, 72>(fw0, Wlds + W0_OFF, tid);
  stageW<64, 64, 64, 72>(fw1, Wlds + W1_OFF, tid);
  stageW<64, 64, 64, 72>(fw2, Wlds + W2_OFF, tid);
  stageW<64, 65, 80, 72>(fw3, Wlds + W3_OFF, tid);
  stageB<64, 64>(fb0, Blds + 0,   tid);
  stageB<64, 64>(fb1, Blds + 64,  tid);
  stageB<64, 64>(fb2, Blds + 128, tid);
  stageB<65, 80>(fb3, Blds + 192, tid);

  if (lane < 16) {
    int row = row0 + lane;
    float dx = dirs[row * 3 + 0];
    float dy = dirs[row * 3 + 1];
    float dz = dirs[row * 3 + 2];
    short8 z8 = {0, 0, 0, 0, 0, 0, 0, 0};
    short8 s07;
    s07[0] = (short)f2bf(0.28209479177387814f);
    s07[1] = (short)f2bf(-0.48860251190291987f * dy);
    s07[2] = (short)f2bf(0.48860251190291987f * dz);
    s07[3] = (short)f2bf(-0.48860251190291987f * dx);
    s07[4] = (short)f2bf(1.0925484305920792f * dx * dy);
    s07[5] = (short)f2bf(-1.0925484305920792f * dy * dz);
    s07[6] = (short)f2bf(0.31539156525252005f * (3.0f * dz * dz - 1.0f));
    s07[7] = (short)f2bf(-1.0925484305920792f * dx * dz);
    short8 s8v = {0, 0, 0, 0, 0, 0, 0, 0};
    s8v[0] = (short)f2bf(0.5462742152960396f * (dx * dx - dy * dy));
    short* rb = At + lane * 104;
    *(short8*)(rb + 48) = z8;
    *(short8*)(rb + 56) = z8;
    *(short8*)(rb + 64) = s07;
    *(short8*)(rb + 72) = s8v;
    *(short8*)(rb + 80) = z8;
    *(short8*)(rb + 88) = z8;
    *(short8*)(rb + 96) = z8;
  }

  for (int t = lane; t < 16 * LVL; t += 64) {
    int r = t / LVL;
    int l = t - r * LVL;
    int row = row0 + r;
    float res = rp.r[l];
    float x = (pts[row * 3 + 0] + 1.0f) * 0.5f * res;
    float y = (pts[row * 3 + 1] + 1.0f) * 0.5f * res;
    float z = (pts[row * 3 + 2] + 1.0f) * 0.5f * res;
    float fx = floorf(x), fy = floorf(y), fz = floorf(z);
    float w0 = x - fx, w1 = y - fy, w2 = z - fz;
    unsigned c0 = (unsigned)fx, c1 = (unsigned)fy, c2 = (unsigned)fz;
    unsigned ha0 = c0, hb0 = c0 + 1u;
    unsigned ha1 = c1 * 2654435761u, hb1 = ha1 + 2654435761u;
    unsigned ha2 = c2 * 805459861u,  hb2 = ha2 + 805459861u;
    const float* tb = tbl + ((size_t)l << 20);
    float f0 = 0.f, f1 = 0.f;
    #pragma unroll
    for (int i = 0; i < 8; ++i) {
      unsigned h = ((i & 4) ? hb0 : ha0) ^ ((i & 2) ? hb1 : ha1) ^ ((i & 1) ? hb2 : ha2);
      float wt = ((i & 4) ? w0 : 1.f - w0) * ((i & 2) ? w1 : 1.f - w1) * ((i & 1) ? w2 : 1.f - w2);
      float2 fv = *(const float2*)(tb + 2u * (h & TMASK));
      f0 += wt * fv.x;
      f1 += wt * fv.y;
    }
    unsigned pk = (unsigned)f2bf(f0) | ((unsigned)f2bf(f1) << 16);
    *(unsigned*)(At + r * 104 + 2 * l) = pk;
  }

  __syncthreads();

  floatx4 acc[5];

  run_layer<2, 4, 72>(At, Wlds + W0_OFF, m, quad, acc);
  #pragma unroll
  for (int cb = 0; cb < 4; ++cb) {
    float bc = Blds[0 + cb * 16 + m];
    #pragma unroll
    for (int r = 0; r < 4; ++r) {
      float v = geluf(acc[cb][r] + bc);
      At[(quad * 4 + r) * 104 + cb * 16 + m] = (short)f2bf(v);
    }
  }
  run_layer<2, 4, 72>(At, Wlds + W1_OFF, m, quad, acc);
  #pragma unroll
  for (int cb = 0; cb < 4; ++cb) {
    float bc = Blds[64 + cb * 16 + m];
    #pragma unroll
    for (int r = 0; r < 4; ++r) {
      float v = geluf(acc[cb][r] + bc);
      At[(quad * 4 + r) * 104 + cb * 16 + m] = (short)f2bf(v);
    }
  }
  run_layer<2, 4, 72>(At, Wlds + W2_OFF, m, quad, acc);
  #pragma unroll
  for (int cb = 0; cb < 4; ++cb) {
    float bc = Blds[128 + cb * 16 + m];
    #pragma unroll
    for (int r = 0; r < 4; ++r) {
      float v = geluf(acc[cb][r] + bc);
      At[(quad * 4 + r) * 104 + cb * 16 + m] = (short)f2bf(v);
    }
  }
  run_layer<2, 5, 72>(At, Wlds + W3_OFF, m, quad, acc);
  #pragma unroll
  for (int cb = 0; cb < 5; ++cb) {
    int col = cb * 16 + m;
    float bc = Blds[192 + col];
    #pragma unroll
    for (int r = 0; r < 4; ++r) {
      float v = acc[cb][r] + bc;
      int row = quad * 4 + r;
      if (col == 0) {
        float d = (v > 15.f) ? v : __logf(1.0f + __expf(v));
        outp[3 * Nrows + row0 + row] = d;
      } else if (col <= 64) {
        At[row * 104 + (col - 1)] = (short)f2bf(geluf(v));
      }
    }
  }

  __syncthreads();

  stageW<73, 64, 64, 104>(rw0, Wlds + R0_OFF, tid);
  stageW<64, 64, 64,  72>(rw1, Wlds + R1_OFF, tid);
  stageW<64,  3, 16,  72>(rw2, Wlds + R2_OFF, tid);
  stageB<64, 64>(rb0, Blds + 0,   tid);
  stageB<64, 64>(rb1, Blds + 64,  tid);
  stageB< 3, 16>(rb2, Blds + 128, tid);

  __syncthreads();

  run_layer<3, 4, 104>(At, Wlds + R0_OFF, m, quad, acc);
  #pragma unroll
  for (int cb = 0; cb < 4; ++cb) {
    float bc = Blds[0 + cb * 16 + m];
    #pragma unroll
    for (int r = 0; r < 4; ++r) {
      float v = geluf(acc[cb][r] + bc);
      At[(quad * 4 + r) * 104 + cb * 16 + m] = (short)f2bf(v);
    }
  }
  run_layer<2, 4, 72>(At, Wlds + R1_OFF, m, quad, acc);
  #pragma unroll
  for (int cb = 0; cb < 4; ++cb) {
    float bc = Blds[64 + cb * 16 + m];
    #pragma unroll
    for (int r = 0; r < 4; ++r) {
      float v = geluf(acc[cb][r] + bc);
      At[(quad * 4 + r) * 104 + cb * 16 + m] = (short)f2bf(v);
    }
  }
  run_layer<2, 1, 72>(At, Wlds + R2_OFF, m, quad, acc);
  {
    float bc = Blds[128 + m];
    #pragma unroll
    for (int r = 0; r < 4; ++r) {
      float v = acc[0][r] + bc;
      float s = __builtin_amdgcn_rcpf(1.0f + __expf(-v));
      if (m < 3) outp[(row0 + quad * 4 + r) * 3 + m] = s;
    }
  }
}

extern "C" void kernel_launch(void* const* d_in, const int* in_sizes, int n_in,
                              void* d_out, int out_size, void* d_ws, size_t ws_size,
                              hipStream_t stream) {
  ResParams rp;
  double b = exp((log(2048.0) - log(16.0)) / 23.0);
  for (int l = 0; l < LVL; ++l) rp.r[l] = (float)floor(16.0 * pow(b, (double)l));

  const float* pts  = (const float*)d_in[0];
  const float* dirs = (const float*)d_in[1];
  const float* tbl  = (const float*)d_in[2];
  float* outp = (float*)d_out;

  int n = in_sizes[0] / 3;                 // 524288
  int nent = LVL << 19;                    // 12.58M table entries
  size_t enc_b = (size_t)LVL * (size_t)n * 4u;        // 50.3 MB
  size_t img_reserve = 65536;
  size_t tbl_b = (size_t)nent * 4u;                    // 50.3 MB
  size_t full_need = enc_b + img_reserve + tbl_b;
  size_t mid_need  = enc_b + img_reserve;

  unsigned* enc2 = (unsigned*)d_ws;
  short* Wimg = (short*)((char*)d_ws + enc_b);
  float* Bimg = (float*)((char*)d_ws + enc_b + 57344);
  unsigned* tblq = (unsigned*)((char*)d_ws + enc_b + img_reserve);
  int enc_blocks = LVL * (n / 256);
  int mlp_blocks = n / 128;                // 4096

  if (ws_size >= full_need) {
    prep_all<<<8 + 12288, 256, 0, stream>>>(
        (const float*)d_in[3],  (const float*)d_in[4],
        (const float*)d_in[5],  (const float*)d_in[6],
        (const float*)d_in[7],  (const float*)d_in[8],
        (const float*)d_in[9],  (const float*)d_in[10],
        (const float*)d_in[11], (const float*)d_in[12],
        (const float*)d_in[13], (const float*)d_in[14],
        (const float*)d_in[15], (const float*)d_in[16],
        Wimg, Bimg, tbl, tblq, nent, 1);
    hash_encode_k<true><<<enc_blocks, 256, 0, stream>>>(pts, tbl, tblq, enc2, n, rp);
    mlp_g<<<mlp_blocks, 256, 0, stream>>>(dirs, enc2, Wimg, Bimg, outp, n);
  } else if (ws_size >= mid_need) {
    prep_all<<<8, 256, 0, stream>>>(
        (const float*)d_in[3],  (const float*)d_in[4],
        (const float*)d_in[5],  (const float*)d_in[6],
        (const float*)d_in[7],  (const float*)d_in[8],
        (const float*)d_in[9],  (const float*)d_in[10],
        (const float*)d_in[11], (const float*)d_in[12],
        (const float*)d_in[13], (const float*)d_in[14],
        (const float*)d_in[15], (const float*)d_in[16],
        Wimg, Bimg, tbl, nullptr, nent, 0);
    hash_encode_k<false><<<enc_blocks, 256, 0, stream>>>(pts, tbl, nullptr, enc2, n, rp);
    mlp_g<<<mlp_blocks, 256, 0, stream>>>(dirs, enc2, Wimg, Bimg, outp, n);
  } else {
    nerf_fused<<<n / 64, 256, 0, stream>>>(
        pts, dirs, tbl,
        (const float*)d_in[3],  (const float*)d_in[4],
        (const float*)d_in[5],  (const float*)d_in[6],
        (const float*)d_in[7],  (const float*)d_in[8],
        (const float*)d_in[9],  (const float*)d_in[10],
        (const float*)d_in[11], (const float*)d_in[12],
        (const float*)d_in[13], (const float*)d_in[14],
        (const float*)d_in[15], (const float*)d_in[16],
        outp, n, rp);
  }
}

// Round 7
// 526.203 us; speedup vs baseline: 2.4226x; 1.0011x over previous
//
#include <hip/hip_runtime.h>
#include <math.h>

#define LVL 24
#define TMASK ((1u << 19) - 1u)

typedef short short8 __attribute__((ext_vector_type(8)));
typedef float floatx4 __attribute__((ext_vector_type(4)));

struct ResParams { float r[LVL]; };

__device__ __forceinline__ float bf2f(unsigned short b) {
  union { unsigned u; float f; } t; t.u = ((unsigned)b) << 16; return t.f;
}
__device__ __forceinline__ unsigned f2bf(float f) {
  union { float f; unsigned u; } t; t.f = f;
  unsigned u = t.u;
  u += 0x7FFFu + ((u >> 16) & 1u);   // RNE
  return u >> 16;
}
// Fast exact-form gelu: A&S 7.1.26 erf, |err| < 1.5e-7, branch-free.
__device__ __forceinline__ float geluf(float x) {
  float a = fabsf(x) * 0.7071067811865476f;
  float t = __builtin_amdgcn_rcpf(fmaf(0.3275911f, a, 1.0f));
  float p = fmaf(t, 1.061405429f, -1.453152027f);
  p = fmaf(t, p, 1.421413741f);
  p = fmaf(t, p, -0.284496736f);
  p = fmaf(t, p, 0.254829592f);
  float er = 1.0f - p * t * __expf(-a * a);
  return 0.5f * x * (1.0f + copysignf(er, x));
}
__device__ __forceinline__ floatx4 mfma16(short8 a, short8 b, floatx4 c) {
  return __builtin_amdgcn_mfma_f32_16x16x32_bf16(a, b, c, 0, 0, 0);
}

// Fragment-ordered weight image offsets (shorts / short8).
#define L0_W 0
#define L1_W 4096
#define L2_W 8192
#define L3_W 12288
#define L4_W 17408
#define L5_W 23552
#define L6_W 27648
#define L0_F 0
#define L1_F 512
#define L2_F 1024
#define L3_F 1536
#define L4_F 2176
#define L5_F 2944
#define L6_F 3456

// ---------------------------------------------------------------------------
// Prep (fused): blocks 0-7 build fragment-ordered bf16 weight images + bias
// image; blocks 8+ pack the f32 table to bf16x2 (vectorized float4->uint2).
// ---------------------------------------------------------------------------
__device__ void prepF(const float* w, short* dst, int K, int NOUT, int KCH, int CBS) {
  int total = KCH * CBS * 64 * 8;
  for (int i = threadIdx.x; i < total; i += 256) {
    int j = i & 7;
    int lane = (i >> 3) & 63;
    int cbc = i >> 9;
    int cb = cbc % CBS;
    int c  = cbc / CBS;
    int n = cb * 16 + (lane & 15);
    int k = c * 32 + (lane >> 4) * 8 + j;
    short v = 0;
    if (k < K && n < NOUT) v = (short)f2bf(w[k * NOUT + n]);
    dst[i] = v;
  }
}
__global__ __launch_bounds__(256) void prep_all(
    const float* __restrict__ fw0, const float* __restrict__ fb0,
    const float* __restrict__ fw1, const float* __restrict__ fb1,
    const float* __restrict__ fw2, const float* __restrict__ fb2,
    const float* __restrict__ fw3, const float* __restrict__ fb3,
    const float* __restrict__ rw0, const float* __restrict__ rb0,
    const float* __restrict__ rw1, const float* __restrict__ rb1,
    const float* __restrict__ rw2, const float* __restrict__ rb2,
    short* __restrict__ Wimg, float* __restrict__ Bimg,
    const float* __restrict__ tbl, unsigned* __restrict__ tblq, int nent,
    int pack_on)
{
  int b = blockIdx.x, tid = threadIdx.x;
  if (b >= 8) {
    if (!pack_on) return;
    int g = (b - 8) * 256 + tid;
    int stride = (gridDim.x - 8) * 256;
    const float4* t4 = (const float4*)tbl;
    uint2* q2 = (uint2*)tblq;
    int n4 = nent >> 1;                 // one float4 = 2 entries
    for (int e = g; e < n4; e += stride) {
      float4 v = t4[e];
      uint2 o;
      o.x = f2bf(v.x) | (f2bf(v.y) << 16);
      o.y = f2bf(v.z) | (f2bf(v.w) << 16);
      q2[e] = o;
    }
    return;
  }
  switch (b) {
    case 0: prepF(fw0, Wimg + L0_W, 48, 64, 2, 4); break;
    case 1: prepF(fw1, Wimg + L1_W, 64, 64, 2, 4); break;
    case 2: prepF(fw2, Wimg + L2_W, 64, 64, 2, 4); break;
    case 3: prepF(fw3, Wimg + L3_W, 64, 65, 2, 5); break;
    case 4: prepF(rw0, Wimg + L4_W, 73, 64, 3, 4); break;
    case 5: prepF(rw1, Wimg + L5_W, 64, 64, 2, 4); break;
    case 6: prepF(rw2, Wimg + L6_W, 64,  3, 2, 1); break;
    case 7:
      if (tid < 64) {
        Bimg[tid]       = fb0[tid];
        Bimg[64 + tid]  = fb1[tid];
        Bimg[128 + tid] = fb2[tid];
        Bimg[272 + tid] = rb0[tid];
        Bimg[336 + tid] = rb1[tid];
      }
      if (tid < 80) Bimg[192 + tid] = (tid < 65) ? fb3[tid] : 0.0f;
      if (tid < 16) Bimg[400 + tid] = (tid < 3) ? rb2[tid] : 0.0f;
      break;
  }
}

// ---------------------------------------------------------------------------
// Hash-grid encode (unchanged from r6: at the L2 gather-request roofline).
// ---------------------------------------------------------------------------
template<bool PACKED>
__global__ __launch_bounds__(256) void hash_encode_k(
    const float* __restrict__ pts, const float* __restrict__ tbl,
    const unsigned* __restrict__ tblq, unsigned* __restrict__ enc2,
    int N, ResParams rp)
{
  __shared__ float pbuf[4][192];
  int bid  = blockIdx.x;
  int wave = threadIdx.x >> 6;
  int lane = threadIdx.x & 63;
  int l    = bid >> 11;
  int p0   = ((bid & 2047) << 8) + wave * 64;
  int p    = p0 + lane;
  float res = rp.r[l];

  {
    const float* pf = pts + (size_t)p0 * 3;
    pbuf[wave][lane]       = pf[lane];
    pbuf[wave][64 + lane]  = pf[64 + lane];
    pbuf[wave][128 + lane] = pf[128 + lane];
  }
  float x = (pbuf[wave][lane * 3 + 0] + 1.0f) * 0.5f * res;
  float y = (pbuf[wave][lane * 3 + 1] + 1.0f) * 0.5f * res;
  float z = (pbuf[wave][lane * 3 + 2] + 1.0f) * 0.5f * res;

  float fx = floorf(x), fy = floorf(y), fz = floorf(z);
  float w0 = x - fx, w1 = y - fy, w2 = z - fz;
  unsigned c0 = (unsigned)fx, c1 = (unsigned)fy, c2 = (unsigned)fz;
  unsigned hy0 = c1 * 2654435761u, hy1 = hy0 + 2654435761u;
  unsigned hz0 = c2 * 805459861u,  hz1 = hz0 + 805459861u;
  bool ceven = ((c0 & 1u) == 0u);

  const unsigned* tq = PACKED ? (tblq + ((size_t)l << 19)) : nullptr;
  const float*    tf = PACKED ? nullptr : (tbl + ((size_t)l << 20));

  float f0 = 0.f, f1 = 0.f;
  #pragma unroll
  for (int yz = 0; yz < 4; ++yz) {
    unsigned hyz = ((yz & 2) ? hy1 : hy0) ^ ((yz & 1) ? hz1 : hz0);
    float wyz = ((yz & 2) ? w1 : 1.f - w1) * ((yz & 1) ? w2 : 1.f - w2);
    unsigned h0 = (c0 ^ hyz) & TMASK;
    unsigned h1 = ((c0 + 1u) ^ hyz) & TMASK;
    float e00, e01, e10, e11;
    if constexpr (PACKED) {
      unsigned v0, v1;
      if (ceven) {                              // h1 == h0^1
        uint2 v = *(const uint2*)(tq + (h0 & ~1u));
        v0 = (h0 & 1u) ? v.y : v.x;
        v1 = (h0 & 1u) ? v.x : v.y;
      } else {
        v0 = tq[h0];
        v1 = tq[h1];
      }
      e00 = bf2f((unsigned short)(v0 & 0xffffu)); e01 = bf2f((unsigned short)(v0 >> 16));
      e10 = bf2f((unsigned short)(v1 & 0xffffu)); e11 = bf2f((unsigned short)(v1 >> 16));
    } else {
      if (ceven) {
        float4 v = *(const float4*)(tf + 2u * (h0 & ~1u));
        if (h0 & 1u) { e00 = v.z; e01 = v.w; e10 = v.x; e11 = v.y; }
        else         { e00 = v.x; e01 = v.y; e10 = v.z; e11 = v.w; }
      } else {
        float2 a = *(const float2*)(tf + 2u * h0);
        float2 b = *(const float2*)(tf + 2u * h1);
        e00 = a.x; e01 = a.y; e10 = b.x; e11 = b.y;
      }
    }
    float wa = (1.f - w0) * wyz, wb = w0 * wyz;
    f0 += wa * e00 + wb * e10;
    f1 += wa * e01 + wb * e11;
  }
  enc2[l * N + p] = f2bf(f0) | (f2bf(f1) << 16);
}

// ---------------------------------------------------------------------------
// MLP: 32 rows/wave, B-fragments software-pipelined: layer i+1's global
// fragment loads issue right after layer i's MFMAs consume the register
// buffer, hiding B latency behind the epilogue VALU.
// ---------------------------------------------------------------------------
template<int NF>
__device__ __forceinline__ void loadB(const short8* Wf, int lane, short8* B) {
  #pragma unroll
  for (int i = 0; i < NF; ++i) B[i] = Wf[i * 64 + lane];
}
template<int KCH, int CBS>
__device__ __forceinline__ void mfma_layer(const short* At, const short8* B,
                                           int m, int quad,
                                           floatx4* acc0, floatx4* acc1) {
  #pragma unroll
  for (int cb = 0; cb < CBS; ++cb) {
    acc0[cb] = (floatx4){0.f, 0.f, 0.f, 0.f};
    acc1[cb] = (floatx4){0.f, 0.f, 0.f, 0.f};
  }
  #pragma unroll
  for (int c = 0; c < KCH; ++c) {
    short8 a0 = *(const short8*)(At + m * 104 + c * 32 + quad * 8);
    short8 a1 = *(const short8*)(At + (16 + m) * 104 + c * 32 + quad * 8);
    #pragma unroll
    for (int cb = 0; cb < CBS; ++cb) {
      acc0[cb] = mfma16(a0, B[c * CBS + cb], acc0[cb]);
      acc1[cb] = mfma16(a1, B[c * CBS + cb], acc1[cb]);
    }
  }
}

__global__ __launch_bounds__(256, 4) void mlp_g(
    const float* __restrict__ dirs,
    const unsigned* __restrict__ enc2,
    const short* __restrict__ Wimg, const float* __restrict__ Bimg,
    float* __restrict__ outp, int Nrows)
{
  __shared__ __align__(16) short Atile[4 * 32 * 104];
  __shared__ __align__(16) float Blds[416];

  const int tid  = threadIdx.x;
  const int wave = tid >> 6;
  const int lane = tid & 63;
  const int m    = lane & 15;
  const int quad = lane >> 4;
  const int row0 = blockIdx.x * 128 + wave * 32;
  short* At = Atile + wave * (32 * 104);
  const short8* Wf = (const short8*)Wimg;

  short8 B[12];
  loadB<8>(Wf + L0_F, lane, B);          // L0 fragments in flight during staging

  if (tid < 104) ((float4*)Blds)[tid] = ((const float4*)Bimg)[tid];

  // SH3 dirs at k=64..72, zeros k=48..63 / 73..103 (32 rows: lanes 0..31)
  if (lane < 32) {
    int row = row0 + lane;
    float dx = dirs[row * 3 + 0];
    float dy = dirs[row * 3 + 1];
    float dz = dirs[row * 3 + 2];
    short8 z8 = {0, 0, 0, 0, 0, 0, 0, 0};
    short8 s07;
    s07[0] = (short)f2bf(0.28209479177387814f);
    s07[1] = (short)f2bf(-0.48860251190291987f * dy);
    s07[2] = (short)f2bf(0.48860251190291987f * dz);
    s07[3] = (short)f2bf(-0.48860251190291987f * dx);
    s07[4] = (short)f2bf(1.0925484305920792f * dx * dy);
    s07[5] = (short)f2bf(-1.0925484305920792f * dy * dz);
    s07[6] = (short)f2bf(0.31539156525252005f * (3.0f * dz * dz - 1.0f));
    s07[7] = (short)f2bf(-1.0925484305920792f * dx * dz);
    short8 s8v = {0, 0, 0, 0, 0, 0, 0, 0};
    s8v[0] = (short)f2bf(0.5462742152960396f * (dx * dx - dy * dy));
    short* rb = At + lane * 104;
    *(short8*)(rb + 48) = z8;
    *(short8*)(rb + 56) = z8;
    *(short8*)(rb + 64) = s07;
    *(short8*)(rb + 72) = s8v;
    *(short8*)(rb + 80) = z8;
    *(short8*)(rb + 88) = z8;
    *(short8*)(rb + 96) = z8;
  }

  // A-tile k=0..47 from enc2 (wave-private): 32 rows x 24 levels
  for (int i = lane; i < 32 * LVL; i += 64) {
    int l = i >> 5;
    int r = i & 31;
    unsigned v = enc2[l * Nrows + row0 + r];
    *(unsigned*)(At + r * 104 + 2 * l) = v;
  }

  __syncthreads();   // Blds visibility (Atile is wave-private)

  floatx4 acc0[5], acc1[5];

#define EPI_GELU(BOFF)                                                        \
  _Pragma("unroll")                                                           \
  for (int cb = 0; cb < 4; ++cb) {                                            \
    float bc = Blds[(BOFF) + cb * 16 + m];                                    \
    _Pragma("unroll")                                                         \
    for (int r = 0; r < 4; ++r) {                                             \
      At[(quad * 4 + r) * 104 + cb * 16 + m]      = (short)f2bf(geluf(acc0[cb][r] + bc)); \
      At[(16 + quad * 4 + r) * 104 + cb * 16 + m] = (short)f2bf(geluf(acc1[cb][r] + bc)); \
    }                                                                         \
  }

  // L0
  mfma_layer<2, 4>(At, B, m, quad, acc0, acc1);
  loadB<8>(Wf + L1_F, lane, B);
  EPI_GELU(0)
  // L1
  mfma_layer<2, 4>(At, B, m, quad, acc0, acc1);
  loadB<8>(Wf + L2_F, lane, B);
  EPI_GELU(64)
  // L2
  mfma_layer<2, 4>(At, B, m, quad, acc0, acc1);
  loadB<10>(Wf + L3_F, lane, B);
  EPI_GELU(128)
  // L3: col0 -> softplus -> density ; cols 1..64 -> gelu -> k=0..63
  mfma_layer<2, 5>(At, B, m, quad, acc0, acc1);
  loadB<12>(Wf + L4_F, lane, B);
  #pragma unroll
  for (int cb = 0; cb < 5; ++cb) {
    int col = cb * 16 + m;
    float bc = Blds[192 + col];
    #pragma unroll
    for (int r = 0; r < 4; ++r) {
      #pragma unroll
      for (int t = 0; t < 2; ++t) {
        float v = (t ? acc1[cb][r] : acc0[cb][r]) + bc;
        int row = t * 16 + quad * 4 + r;
        if (col == 0) {
          float d = (v > 15.f) ? v : __logf(1.0f + __expf(v));
          outp[3 * Nrows + row0 + row] = d;
        } else if (col <= 64) {
          At[row * 104 + (col - 1)] = (short)f2bf(geluf(v));
        }
      }
    }
  }
  // L4: [feat64 | sh9 | 0pad] (K=96) -> 64, gelu
  mfma_layer<3, 4>(At, B, m, quad, acc0, acc1);
  loadB<8>(Wf + L5_F, lane, B);
  EPI_GELU(272)
  // L5
  mfma_layer<2, 4>(At, B, m, quad, acc0, acc1);
  loadB<2>(Wf + L6_F, lane, B);
  EPI_GELU(336)
  // L6: 64 -> 3, sigmoid -> rgb
  mfma_layer<2, 1>(At, B, m, quad, acc0, acc1);
  {
    float bc = Blds[400 + m];
    #pragma unroll
    for (int r = 0; r < 4; ++r) {
      #pragma unroll
      for (int t = 0; t < 2; ++t) {
        float v = (t ? acc1[0][r] : acc0[0][r]) + bc;
        float s = __builtin_amdgcn_rcpf(1.0f + __expf(-v));
        int row = t * 16 + quad * 4 + r;
        if (m < 3) outp[(row0 + row) * 3 + m] = s;
      }
    }
  }
#undef EPI_GELU
}

// ---------------------------------------------------------------------------
// Fallback: fully fused kernel (used only if ws too small).
// ---------------------------------------------------------------------------
#define W0_OFF 0
#define W1_OFF 4608
#define W2_OFF 9216
#define W3_OFF 13824
#define R0_OFF 0
#define R1_OFF 6656
#define R2_OFF 11264

template<int K, int NOUT, int NROWS, int STRIDE>
__device__ void stageW(const float* w, short* dst, int tid) {
  for (int i = tid; i < NROWS * STRIDE; i += 256) {
    int n = i / STRIDE;
    int k = i - n * STRIDE;
    short v = 0;
    if (n < NOUT && k < K) v = (short)f2bf(w[k * NOUT + n]);
    dst[i] = v;
  }
}
template<int NOUT, int NPAD>
__device__ void stageB(const float* b, float* dst, int tid) {
  for (int i = tid; i < NPAD; i += 256) dst[i] = (i < NOUT) ? b[i] : 0.0f;
}
template<int KCH, int CBS, int WSTRIDE>
__device__ __forceinline__ void run_layer(const short* At, const short* Wb,
                                          int m, int quad, floatx4* acc) {
  #pragma unroll
  for (int cb = 0; cb < CBS; ++cb) acc[cb] = (floatx4){0.f, 0.f, 0.f, 0.f};
  #pragma unroll
  for (int c = 0; c < KCH; ++c) {
    short8 a = *(const short8*)(At + m * 104 + c * 32 + quad * 8);
    #pragma unroll
    for (int cb = 0; cb < CBS; ++cb) {
      short8 b = *(const short8*)(Wb + (cb * 16 + m) * WSTRIDE + c * 32 + quad * 8);
      acc[cb] = mfma16(a, b, acc[cb]);
    }
  }
}

__global__ __launch_bounds__(256, 2) void nerf_fused(
    const float* __restrict__ pts,
    const float* __restrict__ dirs,
    const float* __restrict__ tbl,
    const float* __restrict__ fw0, const float* __restrict__ fb0,
    const float* __restrict__ fw1, const float* __restrict__ fb1,
    const float* __restrict__ fw2, const float* __restrict__ fb2,
    const float* __restrict__ fw3, const float* __restrict__ fb3,
    const float* __restrict__ rw0, const float* __restrict__ rb0,
    const float* __restrict__ rw1, const float* __restrict__ rb1,
    const float* __restrict__ rw2, const float* __restrict__ rb2,
    float* __restrict__ outp, int Nrows, ResParams rp)
{
  __shared__ __align__(16) short Wlds[19584];
  __shared__ __align__(16) float Blds[272];
  __shared__ __align__(16) short Atile[4 * 16 * 104];

  const int tid  = threadIdx.x;
  const int wave = tid >> 6;
  const int lane = tid & 63;
  const int m    = lane & 15;
  const int quad = lane >> 4;
  const int row0 = blockIdx.x * 64 + wave * 16;
  short* At = Atile + wave * (16 * 104);

  stageW<48, 64, 64, 72>(fw0, Wlds + W0_OFF, tid);
  stageW<64, 64, 64, 72>(fw1, Wlds + W1_OFF, tid);
  stageW<64, 64, 64, 72>(fw2, Wlds + W2_OFF, tid);
  stageW<64, 65, 80, 72>(fw3, Wlds + W3_OFF, tid);
  stageB<64, 64>(fb0, Blds + 0,   tid);
  stageB<64, 64>(fb1, Blds + 64,  tid);
  stageB<64, 64>(fb2, Blds + 128, tid);
  stageB<65, 80>(fb3, Blds + 192, tid);

  if (lane < 16) {
    int row = row0 + lane;
    float dx = dirs[row * 3 + 0];
    float dy = dirs[row * 3 + 1];
    float dz = dirs[row * 3 + 2];
    short8 z8 = {0, 0, 0, 0, 0, 0, 0, 0};
    short8 s07;
    s07[0] = (short)f2bf(0.28209479177387814f);
    s07[1] = (short)f2bf(-0.48860251190291987f * dy);
    s07[2] = (short)f2bf(0.48860251190291987f * dz);
    s07[3] = (short)f2bf(-0.48860251190291987f * dx);
    s07[4] = (short)f2bf(1.0925484305920792f * dx * dy);
    s07[5] = (short)f2bf(-1.0925484305920792f * dy * dz);
    s07[6] = (short)f2bf(0.31539156525252005f * (3.0f * dz * dz - 1.0f));
    s07[7] = (short)f2bf(-1.0925484305920792f * dx * dz);
    short8 s8v = {0, 0, 0, 0, 0, 0, 0, 0};
    s8v[0] = (short)f2bf(0.5462742152960396f * (dx * dx - dy * dy));
    short* rb = At + lane * 104;
    *(short8*)(rb + 48) = z8;
    *(short8*)(rb + 56) = z8;
    *(short8*)(rb + 64) = s07;
    *(short8*)(rb + 72) = s8v;
    *(short8*)(rb + 80) = z8;
    *(short8*)(rb + 88) = z8;
    *(short8*)(rb + 96) = z8;
  }

  for (int t = lane; t < 16 * LVL; t += 64) {
    int r = t / LVL;
    int l = t - r * LVL;
    int row = row0 + r;
    float res = rp.r[l];
    float x = (pts[row * 3 + 0] + 1.0f) * 0.5f * res;
    float y = (pts[row * 3 + 1] + 1.0f) * 0.5f * res;
    float z = (pts[row * 3 + 2] + 1.0f) * 0.5f * res;
    float fx = floorf(x), fy = floorf(y), fz = floorf(z);
    float w0 = x - fx, w1 = y - fy, w2 = z - fz;
    unsigned c0 = (unsigned)fx, c1 = (unsigned)fy, c2 = (unsigned)fz;
    unsigned ha0 = c0, hb0 = c0 + 1u;
    unsigned ha1 = c1 * 2654435761u, hb1 = ha1 + 2654435761u;
    unsigned ha2 = c2 * 805459861u,  hb2 = ha2 + 805459861u;
    const float* tb = tbl + ((size_t)l << 20);
    float f0 = 0.f, f1 = 0.f;
    #pragma unroll
    for (int i = 0; i < 8; ++i) {
      unsigned h = ((i & 4) ? hb0 : ha0) ^ ((i & 2) ? hb1 : ha1) ^ ((i & 1) ? hb2 : ha2);
      float wt = ((i & 4) ? w0 : 1.f - w0) * ((i & 2) ? w1 : 1.f - w1) * ((i & 1) ? w2 : 1.f - w2);
      float2 fv = *(const float2*)(tb + 2u * (h & TMASK));
      f0 += wt * fv.x;
      f1 += wt * fv.y;
    }
    unsigned pk = f2bf(f0) | (f2bf(f1) << 16);
    *(unsigned*)(At + r * 104 + 2 * l) = pk;
  }

  __syncthreads();

  floatx4 acc[5];

  run_layer<2, 4, 72>(At, Wlds + W0_OFF, m, quad, acc);
  #pragma unroll
  for (int cb = 0; cb < 4; ++cb) {
    float bc = Blds[0 + cb * 16 + m];
    #pragma unroll
    for (int r = 0; r < 4; ++r) {
      float v = geluf(acc[cb][r] + bc);
      At[(quad * 4 + r) * 104 + cb * 16 + m] = (short)f2bf(v);
    }
  }
  run_layer<2, 4, 72>(At, Wlds + W1_OFF, m, quad, acc);
  #pragma unroll
  for (int cb = 0; cb < 4; ++cb) {
    float bc = Blds[64 + cb * 16 + m];
    #pragma unroll
    for (int r = 0; r < 4; ++r) {
      float v = geluf(acc[cb][r] + bc);
      At[(quad * 4 + r) * 104 + cb * 16 + m] = (short)f2bf(v);
    }
  }
  run_layer<2, 4, 72>(At, Wlds + W2_OFF, m, quad, acc);
  #pragma unroll
  for (int cb = 0; cb < 4; ++cb) {
    float bc = Blds[128 + cb * 16 + m];
    #pragma unroll
    for (int r = 0; r < 4; ++r) {
      float v = geluf(acc[cb][r] + bc);
      At[(quad * 4 + r) * 104 + cb * 16 + m] = (short)f2bf(v);
    }
  }
  run_layer<2, 5, 72>(At, Wlds + W3_OFF, m, quad, acc);
  #pragma unroll
  for (int cb = 0; cb < 5; ++cb) {
    int col = cb * 16 + m;
    float bc = Blds[192 + col];
    #pragma unroll
    for (int r = 0; r < 4; ++r) {
      float v = acc[cb][r] + bc;
      int row = quad * 4 + r;
      if (col == 0) {
        float d = (v > 15.f) ? v : __logf(1.0f + __expf(v));
        outp[3 * Nrows + row0 + row] = d;
      } else if (col <= 64) {
        At[row * 104 + (col - 1)] = (short)f2bf(geluf(v));
      }
    }
  }

  __syncthreads();

  stageW<73, 64, 64, 104>(rw0, Wlds + R0_OFF, tid);
  stageW<64, 64, 64,  72>(rw1, Wlds + R1_OFF, tid);
  stageW<64,  3, 16,  72>(rw2, Wlds + R2_OFF, tid);
  stageB<64, 64>(rb0, Blds + 0,   tid);
  stageB<64, 64>(rb1, Blds + 64,  tid);
  stageB< 3, 16>(rb2, Blds + 128, tid);

  __syncthreads();

  run_layer<3, 4, 104>(At, Wlds + R0_OFF, m, quad, acc);
  #pragma unroll
  for (int cb = 0; cb < 4; ++cb) {
    float bc = Blds[0 + cb * 16 + m];
    #pragma unroll
    for (int r = 0; r < 4; ++r) {
      float v = geluf(acc[cb][r] + bc);
      At[(quad * 4 + r) * 104 + cb * 16 + m] = (short)f2bf(v);
    }
  }
  run_layer<2, 4, 72>(At, Wlds + R1_OFF, m, quad, acc);
  #pragma unroll
  for (int cb = 0; cb < 4; ++cb) {
    float bc = Blds[64 + cb * 16 + m];
    #pragma unroll
    for (int r = 0; r < 4; ++r) {
      float v = geluf(acc[cb][r] + bc);
      At[(quad * 4 + r) * 104 + cb * 16 + m] = (short)f2bf(v);
    }
  }
  run_layer<2, 1, 72>(At, Wlds + R2_OFF, m, quad, acc);
  {
    float bc = Blds[128 + m];
    #pragma unroll
    for (int r = 0; r < 4; ++r) {
      float v = acc[0][r] + bc;
      float s = __builtin_amdgcn_rcpf(1.0f + __expf(-v));
      if (m < 3) outp[(row0 + quad * 4 + r) * 3 + m] = s;
    }
  }
}

extern "C" void kernel_launch(void* const* d_in, const int* in_sizes, int n_in,
                              void* d_out, int out_size, void* d_ws, size_t ws_size,
                              hipStream_t stream) {
  ResParams rp;
  double b = exp((log(2048.0) - log(16.0)) / 23.0);
  for (int l = 0; l < LVL; ++l) rp.r[l] = (float)floor(16.0 * pow(b, (double)l));

  const float* pts  = (const float*)d_in[0];
  const float* dirs = (const float*)d_in[1];
  const float* tbl  = (const float*)d_in[2];
  float* outp = (float*)d_out;

  int n = in_sizes[0] / 3;                 // 524288
  int nent = LVL << 19;                    // 12.58M table entries
  size_t enc_b = (size_t)LVL * (size_t)n * 4u;        // 50.3 MB
  size_t img_reserve = 65536;
  size_t tbl_b = (size_t)nent * 4u;                    // 50.3 MB
  size_t full_need = enc_b + img_reserve + tbl_b;
  size_t mid_need  = enc_b + img_reserve;

  unsigned* enc2 = (unsigned*)d_ws;
  short* Wimg = (short*)((char*)d_ws + enc_b);
  float* Bimg = (float*)((char*)d_ws + enc_b + 57344);
  unsigned* tblq = (unsigned*)((char*)d_ws + enc_b + img_reserve);
  int enc_blocks = LVL * (n / 256);
  int mlp_blocks = n / 128;                // 4096

  if (ws_size >= full_need) {
    prep_all<<<8 + 6144, 256, 0, stream>>>(
        (const float*)d_in[3],  (const float*)d_in[4],
        (const float*)d_in[5],  (const float*)d_in[6],
        (const float*)d_in[7],  (const float*)d_in[8],
        (const float*)d_in[9],  (const float*)d_in[10],
        (const float*)d_in[11], (const float*)d_in[12],
        (const float*)d_in[13], (const float*)d_in[14],
        (const float*)d_in[15], (const float*)d_in[16],
        Wimg, Bimg, tbl, tblq, nent, 1);
    hash_encode_k<true><<<enc_blocks, 256, 0, stream>>>(pts, tbl, tblq, enc2, n, rp);
    mlp_g<<<mlp_blocks, 256, 0, stream>>>(dirs, enc2, Wimg, Bimg, outp, n);
  } else if (ws_size >= mid_need) {
    prep_all<<<8, 256, 0, stream>>>(
        (const float*)d_in[3],  (const float*)d_in[4],
        (const float*)d_in[5],  (const float*)d_in[6],
        (const float*)d_in[7],  (const float*)d_in[8],
        (const float*)d_in[9],  (const float*)d_in[10],
        (const float*)d_in[11], (const float*)d_in[12],
        (const float*)d_in[13], (const float*)d_in[14],
        (const float*)d_in[15], (const float*)d_in[16],
        Wimg, Bimg, tbl, nullptr, nent, 0);
    hash_encode_k<false><<<enc_blocks, 256, 0, stream>>>(pts, tbl, nullptr, enc2, n, rp);
    mlp_g<<<mlp_blocks, 256, 0, stream>>>(dirs, enc2, Wimg, Bimg, outp, n);
  } else {
    nerf_fused<<<n / 64, 256, 0, stream>>>(
        pts, dirs, tbl,
        (const float*)d_in[3],  (const float*)d_in[4],
        (const float*)d_in[5],  (const float*)d_in[6],
        (const float*)d_in[7],  (const float*)d_in[8],
        (const float*)d_in[9],  (const float*)d_in[10],
        (const float*)d_in[11], (const float*)d_in[12],
        (const float*)d_in[13], (const float*)d_in[14],
        (const float*)d_in[15], (const float*)d_in[16],
        outp, n, rp);
  }
}